// Round 4
// baseline (1294.329 us; speedup 1.0000x reference)
//
#include <hip/hip_runtime.h>
#include <math.h>

#define D_MODEL 1024
#define D_INNER 2048
#define D_STATE 16
#define D_CONV  4
#define DT_RANK 64
#define NB      2
#define LSEQ    1024
#define NROWS   (NB * LSEQ)   // 2048
#define LN_EPS  1e-5f
#define N_LAYER 4
#define NCHUNK  16
#define TCH     (LSEQ / NCHUNK)   // 64 steps per chunk

__device__ inline unsigned bfbits(float f) {
    unsigned u = __float_as_uint(f);
    return (u + 0x7fffu + ((u >> 16) & 1u)) >> 16;  // RNE
}

// ---------------------------------------------------------------------------
// Fused residual-add + LayerNorm. bf16out=1: emit bf16; 0: fp32.
// ---------------------------------------------------------------------------
__device__ inline float wave_sum(float s) {
    #pragma unroll
    for (int m = 1; m < 64; m <<= 1) s += __shfl_xor(s, m, 64);
    return s;
}

__global__ __launch_bounds__(256)
void add_ln_kernel(const float* __restrict__ add, float* __restrict__ residual,
                   const float* __restrict__ w, const float* __restrict__ b,
                   void* __restrict__ out, int first, int bf16out)
{
    int row = blockIdx.x;
    int tid = threadIdx.x;
    size_t base = (size_t)row * D_MODEL + tid * 4;

    float4 v = *(const float4*)(add + base);
    if (!first) {
        float4 r = *(const float4*)(residual + base);
        v.x += r.x; v.y += r.y; v.z += r.z; v.w += r.w;
    }
    *(float4*)(residual + base) = v;

    __shared__ float red[8];
    float s = v.x + v.y + v.z + v.w;
    s = wave_sum(s);
    if ((tid & 63) == 0) red[tid >> 6] = s;
    __syncthreads();
    float mu = (red[0] + red[1] + red[2] + red[3]) * (1.0f / D_MODEL);

    float dx = v.x - mu, dy = v.y - mu, dz = v.z - mu, dw2 = v.w - mu;
    float s2 = dx*dx + dy*dy + dz*dz + dw2*dw2;
    s2 = wave_sum(s2);
    if ((tid & 63) == 0) red[4 + (tid >> 6)] = s2;
    __syncthreads();
    float var = (red[4] + red[5] + red[6] + red[7]) * (1.0f / D_MODEL);
    float rs = rsqrtf(var + LN_EPS);

    float4 wv = *(const float4*)(w + tid * 4);
    float4 bv = *(const float4*)(b + tid * 4);
    float4 o;
    o.x = dx  * rs * wv.x + bv.x;
    o.y = dy  * rs * wv.y + bv.y;
    o.z = dz  * rs * wv.z + bv.z;
    o.w = dw2 * rs * wv.w + bv.w;
    if (bf16out) {
        ushort4 ov;
        ov.x = (unsigned short)bfbits(o.x);
        ov.y = (unsigned short)bfbits(o.y);
        ov.z = (unsigned short)bfbits(o.z);
        ov.w = (unsigned short)bfbits(o.w);
        *(ushort4*)((unsigned short*)out + base) = ov;
    } else {
        *(float4*)((float*)out + base) = o;
    }
}

// ---------------------------------------------------------------------------
// fp32 -> bf16 bulk convert (weights). grid*256*4 must equal element count.
// ---------------------------------------------------------------------------
__global__ __launch_bounds__(256)
void f32_to_bf16_kernel(const float* __restrict__ src, unsigned short* __restrict__ dst)
{
    int i = blockIdx.x * 256 + threadIdx.x;
    float4 v = *(const float4*)(src + (size_t)i * 4);
    ushort4 o;
    o.x = (unsigned short)bfbits(v.x);
    o.y = (unsigned short)bfbits(v.y);
    o.z = (unsigned short)bfbits(v.z);
    o.w = (unsigned short)bfbits(v.w);
    *(ushort4*)(dst + (size_t)i * 4) = o;
}

// ---------------------------------------------------------------------------
// fp32 NT GEMM (dt_proj). A row-major [m][k]. mode 1: softplus(acc+bias).
// tC=1: write C transposed [n][m] (ldc = row stride of n-rows), float4 stores.
// ---------------------------------------------------------------------------
#define TILE 64
#define KT   16

__global__ __launch_bounds__(256)
void gemm_nt(const float* __restrict__ A, const float* __restrict__ B,
             float* __restrict__ C, int M, int N, int K,
             int lda, int ldb, int ldc,
             const float* __restrict__ bias, int mode, int tC)
{
    __shared__ float As[KT][TILE + 4];
    __shared__ float Bs[KT][TILE + 4];

    int tid = threadIdx.x;
    int tx = tid & 15, ty = tid >> 4;
    int m0 = blockIdx.y * TILE;
    int n0 = blockIdx.x * TILE;

    int lr = tid >> 2;
    int lk = (tid & 3) * 4;

    float acc[4][4] = {};

    for (int k0 = 0; k0 < K; k0 += KT) {
        {
            int m = m0 + lr;
            float4 v = *(const float4*)(A + (size_t)m * lda + k0 + lk);
            As[lk + 0][lr] = v.x; As[lk + 1][lr] = v.y;
            As[lk + 2][lr] = v.z; As[lk + 3][lr] = v.w;
        }
        {
            int n = n0 + lr;
            float4 v = make_float4(0.f, 0.f, 0.f, 0.f);
            if (n < N) v = *(const float4*)(B + (size_t)n * ldb + k0 + lk);
            Bs[lk + 0][lr] = v.x; Bs[lk + 1][lr] = v.y;
            Bs[lk + 2][lr] = v.z; Bs[lk + 3][lr] = v.w;
        }
        __syncthreads();
        #pragma unroll
        for (int kk = 0; kk < KT; ++kk) {
            float4 a4 = *(const float4*)&As[kk][ty * 4];
            float4 b4 = *(const float4*)&Bs[kk][tx * 4];
            float av[4] = {a4.x, a4.y, a4.z, a4.w};
            float bv[4] = {b4.x, b4.y, b4.z, b4.w};
            #pragma unroll
            for (int i = 0; i < 4; ++i)
                #pragma unroll
                for (int j = 0; j < 4; ++j)
                    acc[i][j] += av[i] * bv[j];
        }
        __syncthreads();
    }

    if (tC) {
        #pragma unroll
        for (int j = 0; j < 4; ++j) {
            int n = n0 + tx * 4 + j;
            if (n >= N) continue;
            float bsv = (mode == 1) ? bias[n] : 0.f;
            float o[4];
            #pragma unroll
            for (int i = 0; i < 4; ++i) {
                float v = acc[i][j];
                if (mode == 1) {
                    v += bsv;
                    v = (v > 20.f) ? v : log1pf(__expf(v));
                }
                o[i] = v;
            }
            *(float4*)&C[(size_t)n * ldc + m0 + ty * 4] =
                make_float4(o[0], o[1], o[2], o[3]);
        }
    } else {
        #pragma unroll
        for (int i = 0; i < 4; ++i) {
            int m = m0 + ty * 4 + i;
            #pragma unroll
            for (int j = 0; j < 4; ++j) {
                int n = n0 + tx * 4 + j;
                if (n >= N) continue;
                float v = acc[i][j];
                if (mode == 1) {
                    v += bias[n];
                    v = (v > 20.f) ? v : log1pf(__expf(v));
                }
                C[(size_t)m * ldc + n] = v;
            }
        }
    }
}

// ---------------------------------------------------------------------------
// fp32 TN GEMM with split-K (x_proj). A stored TRANSPOSED [k][m] (lda = m-row
// stride). C pre-zeroed; atomicAdd epilogue (unchanged, proven).
// ---------------------------------------------------------------------------
__global__ __launch_bounds__(256)
void gemm_tn_splitk(const float* __restrict__ A, const float* __restrict__ B,
                    float* __restrict__ C, int M, int N, int K,
                    int lda, int ldb, int ldc, int kslice)
{
    __shared__ float As[KT][TILE + 4];
    __shared__ float Bs[KT][TILE + 4];

    int tid = threadIdx.x;
    int tx = tid & 15, ty = tid >> 4;
    int m0 = blockIdx.y * TILE;
    int n0 = blockIdx.x * TILE;
    int kb = blockIdx.z * kslice;

    int lr = tid >> 2;
    int lk = (tid & 3) * 4;
    int kk2 = tid >> 4;         // 0..15 (A staging: k row)
    int mm  = (tid & 15) * 4;   // 0..60 (A staging: m col)

    float acc[4][4] = {};

    for (int k0 = kb; k0 < kb + kslice; k0 += KT) {
        {
            float4 v = *(const float4*)(A + (size_t)(k0 + kk2) * lda + m0 + mm);
            *(float4*)&As[kk2][mm] = v;
        }
        {
            int n = n0 + lr;
            float4 v = make_float4(0.f, 0.f, 0.f, 0.f);
            if (n < N) v = *(const float4*)(B + (size_t)n * ldb + k0 + lk);
            Bs[lk + 0][lr] = v.x; Bs[lk + 1][lr] = v.y;
            Bs[lk + 2][lr] = v.z; Bs[lk + 3][lr] = v.w;
        }
        __syncthreads();
        #pragma unroll
        for (int kk = 0; kk < KT; ++kk) {
            float4 a4 = *(const float4*)&As[kk][ty * 4];
            float4 b4 = *(const float4*)&Bs[kk][tx * 4];
            float av[4] = {a4.x, a4.y, a4.z, a4.w};
            float bv[4] = {b4.x, b4.y, b4.z, b4.w};
            #pragma unroll
            for (int i = 0; i < 4; ++i)
                #pragma unroll
                for (int j = 0; j < 4; ++j)
                    acc[i][j] += av[i] * bv[j];
        }
        __syncthreads();
    }

    #pragma unroll
    for (int i = 0; i < 4; ++i) {
        int m = m0 + ty * 4 + i;
        #pragma unroll
        for (int j = 0; j < 4; ++j) {
            int n = n0 + tx * 4 + j;
            if (n < N) atomicAdd(&C[(size_t)m * ldc + n], acc[i][j]);
        }
    }
}

// ---------------------------------------------------------------------------
// bf16 MFMA NT GEMM. tC=1: write C transposed [col][row] via f32x4 stores.
// ---------------------------------------------------------------------------
using bf16x8 = __attribute__((ext_vector_type(8))) short;
using f32x4  = __attribute__((ext_vector_type(4))) float;

#define BBM 128
#define BBN 128
#define BBK 64
#define LDS_S (BBK + 8)   // 72 bf16 -> 144B row stride

__global__ __launch_bounds__(256)
void gemm_bf16_nt(const unsigned short* __restrict__ A, const unsigned short* __restrict__ Bw,
                  float* __restrict__ C, int M, int N, int K, int tC)
{
    __shared__ unsigned short As[BBM * LDS_S];
    __shared__ unsigned short Bs[BBN * LDS_S];

    int tid = threadIdx.x;
    int m0 = blockIdx.y * BBM, n0 = blockIdx.x * BBN;
    int lane = tid & 63, w = tid >> 6;
    int wm = (w >> 1) * 64, wn = (w & 1) * 64;
    int lm = lane & 15, q = lane >> 4;

    int lr = tid >> 3;          // 0..31  (staging row)
    int lc = (tid & 7) * 8;     // 0..56  (staging col, bf16 elems)

    f32x4 acc[4][4] = {};

    for (int k0 = 0; k0 < K; k0 += BBK) {
        #pragma unroll
        for (int r = 0; r < 4; ++r) {
            int row = lr + r * 32;
            uint4 av = *(const uint4*)(A + (size_t)(m0 + row) * K + k0 + lc);
            *(uint4*)&As[row * LDS_S + lc] = av;
        }
        #pragma unroll
        for (int r = 0; r < 4; ++r) {
            int row = lr + r * 32;
            uint4 pv = *(const uint4*)(Bw + (size_t)(n0 + row) * K + k0 + lc);
            *(uint4*)&Bs[row * LDS_S + lc] = pv;
        }
        __syncthreads();
        #pragma unroll
        for (int kk = 0; kk < BBK; kk += 32) {
            bf16x8 af[4], bf[4];
            #pragma unroll
            for (int i = 0; i < 4; ++i)
                af[i] = *(const bf16x8*)&As[(wm + i * 16 + lm) * LDS_S + kk + q * 8];
            #pragma unroll
            for (int j = 0; j < 4; ++j)
                bf[j] = *(const bf16x8*)&Bs[(wn + j * 16 + lm) * LDS_S + kk + q * 8];
            #pragma unroll
            for (int i = 0; i < 4; ++i)
                #pragma unroll
                for (int j = 0; j < 4; ++j)
                    acc[i][j] = __builtin_amdgcn_mfma_f32_16x16x32_bf16(
                        af[i], bf[j], acc[i][j], 0, 0, 0);
        }
        __syncthreads();
    }

    if (tC) {
        #pragma unroll
        for (int i = 0; i < 4; ++i)
            #pragma unroll
            for (int j = 0; j < 4; ++j) {
                int col = n0 + wn + j * 16 + lm;
                int row = m0 + wm + i * 16 + q * 4;
                *(f32x4*)&C[(size_t)col * M + row] = acc[i][j];
            }
    } else {
        #pragma unroll
        for (int i = 0; i < 4; ++i)
            #pragma unroll
            for (int j = 0; j < 4; ++j)
                #pragma unroll
                for (int r = 0; r < 4; ++r) {
                    int row = m0 + wm + i * 16 + q * 4 + r;
                    int col = n0 + wn + j * 16 + lm;
                    C[(size_t)row * N + col] = acc[i][j][r];
                }
    }
}

// ---------------------------------------------------------------------------
// Depthwise causal conv (width 4) + bias + SiLU, fully t-contiguous:
// reads xT rows of xzT [e=d][r], writes xcT [d][r]. 4 outputs/thread.
// ---------------------------------------------------------------------------
__global__ __launch_bounds__(256)
void conv_silu_kernel(const float* __restrict__ xT, const float* __restrict__ cw,
                      const float* __restrict__ cb, float* __restrict__ xcT)
{
    int idx = blockIdx.x * 256 + threadIdx.x;   // 2048 d * 512 quads
    int d  = idx >> 9;
    int rq = (idx & 511) * 4;                   // r = b*1024 + t, quad-aligned
    int t0 = rq & (LSEQ - 1);

    const float* px = xT + (size_t)d * NROWS + rq;
    float4 cur = *(const float4*)px;
    float4 prev = make_float4(0.f, 0.f, 0.f, 0.f);
    if (t0 != 0) prev = *(const float4*)(px - 4);

    float4 wv = *(const float4*)(cw + d * 4);
    float bias = cb[d];

    float s0 = prev.y, s1 = prev.z, s2 = prev.w;
    float s3 = cur.x, s4 = cur.y, s5 = cur.z, s6 = cur.w;

    float o0 = bias + wv.x * s0 + wv.y * s1 + wv.z * s2 + wv.w * s3;
    float o1 = bias + wv.x * s1 + wv.y * s2 + wv.z * s3 + wv.w * s4;
    float o2 = bias + wv.x * s2 + wv.y * s3 + wv.z * s4 + wv.w * s5;
    float o3 = bias + wv.x * s3 + wv.y * s4 + wv.z * s5 + wv.w * s6;

    o0 = o0 / (1.f + __expf(-o0));
    o1 = o1 / (1.f + __expf(-o1));
    o2 = o2 / (1.f + __expf(-o2));
    o3 = o3 / (1.f + __expf(-o3));

    *(float4*)(xcT + (size_t)d * NROWS + rq) = make_float4(o0, o1, o2, o3);
}

// ---------------------------------------------------------------------------
// Transpose dbl's B/C columns (64..95) into bcT [32][NROWS]. LDS tile.
// ---------------------------------------------------------------------------
__global__ __launch_bounds__(256)
void transpose_bc(const float* __restrict__ dbl, float* __restrict__ bcT)
{
    __shared__ float t[32][65];
    int m0 = blockIdx.x * 64;
    int tid = threadIdx.x;
    #pragma unroll
    for (int e = 0; e < 8; ++e) {
        int idx = tid + e * 256;
        int mr = idx >> 5, s = idx & 31;
        t[s][mr] = dbl[(size_t)(m0 + mr) * 96 + 64 + s];
    }
    __syncthreads();
    #pragma unroll
    for (int e = 0; e < 8; ++e) {
        int idx = tid + e * 256;
        int s = idx >> 6, mr = idx & 63;
        bcT[(size_t)s * NROWS + m0 + mr] = t[s][mr];
    }
}

// ---------------------------------------------------------------------------
// Chunked selective scan, v4: all operands t-contiguous (dtT/xcT [d][r],
// bcT [s][r], zT = xzT row D_INNER+d). float4 per 4 steps, 1-group lookahead.
// 8 d's/wave x 2 states/lane, 8192 waves.
// ---------------------------------------------------------------------------
__global__ __launch_bounds__(256)
void scan_pass1(const float* __restrict__ dtT, const float* __restrict__ xcT,
                const float* __restrict__ bcT, const float* __restrict__ Alog,
                float* __restrict__ aPbuf, float* __restrict__ bAbuf)
{
    int tid  = threadIdx.x;
    int lane = tid & 63;
    int wv   = tid >> 6;
    int q  = lane & 7;        // state pair 2q, 2q+1
    int dl = lane >> 3;       // 8 d's per wave
    int blk = blockIdx.x;     // grid = NB * NCHUNK * 64
    int dgq = blk & 63;
    int c  = (blk >> 6) & (NCHUNK - 1);
    int bb = blk >> 10;
    int d  = dgq * 32 + wv * 8 + dl;

    float A0 = -__expf(Alog[d * D_STATE + q * 2 + 0]);
    float A1 = -__expf(Alog[d * D_STATE + q * 2 + 1]);

    size_t rbase = (size_t)bb * LSEQ + (size_t)c * TCH;
    const float4* pdt = (const float4*)(dtT + (size_t)d * NROWS + rbase);
    const float4* pxc = (const float4*)(xcT + (size_t)d * NROWS + rbase);
    const float4* pb0 = (const float4*)(bcT + (size_t)(2 * q + 0) * NROWS + rbase);
    const float4* pb1 = (const float4*)(bcT + (size_t)(2 * q + 1) * NROWS + rbase);

    float aP0 = 1.f, aP1 = 1.f, bA0 = 0.f, bA1 = 0.f;

    float4 dt4 = pdt[0], xc4 = pxc[0], b04 = pb0[0], b14 = pb1[0];

    for (int g = 0; g < TCH / 4; ++g) {
        int gn = (g + 1 < TCH / 4) ? g + 1 : g;
        float4 dtn = pdt[gn], xcn = pxc[gn], b0n = pb0[gn], b1n = pb1[gn];

        #define P1STEP(F) { \
            float dtv = dt4.F, dx = dt4.F * xc4.F; \
            float a0 = __expf(dtv * A0); aP0 *= a0; bA0 = bA0 * a0 + dx * b04.F; \
            float a1 = __expf(dtv * A1); aP1 *= a1; bA1 = bA1 * a1 + dx * b14.F; }
        P1STEP(x) P1STEP(y) P1STEP(z) P1STEP(w)
        #undef P1STEP

        dt4 = dtn; xc4 = xcn; b04 = b0n; b14 = b1n;
    }

    size_t o = ((size_t)(bb * NCHUNK + c) * D_INNER + d) * D_STATE + q * 2;
    *(float2*)(aPbuf + o) = make_float2(aP0, aP1);
    *(float2*)(bAbuf + o) = make_float2(bA0, bA1);
}

__global__ __launch_bounds__(256)
void scan_pass2(const float* __restrict__ dtT, const float* __restrict__ xcT,
                const float* __restrict__ bcT, const float* __restrict__ xzT,
                const float* __restrict__ Alog, const float* __restrict__ Dp,
                const float* __restrict__ aPbuf, const float* __restrict__ bAbuf,
                unsigned short* __restrict__ y)
{
    int tid  = threadIdx.x;
    int lane = tid & 63;
    int wv   = tid >> 6;
    int q  = lane & 7;
    int dl = lane >> 3;
    int blk = blockIdx.x;
    int dgq = blk & 63;
    int c  = (blk >> 6) & (NCHUNK - 1);
    int bb = blk >> 10;
    int d  = dgq * 32 + wv * 8 + dl;

    float A0 = -__expf(Alog[d * D_STATE + q * 2 + 0]);
    float A1 = -__expf(Alog[d * D_STATE + q * 2 + 1]);
    float Dd = Dp[d];

    // prefix compose: batches of 5 (guarded; loads clamped in-bounds)
    float h0 = 0.f, h1 = 0.f;
    for (int cc0 = 0; cc0 < c; cc0 += 5) {
        float2 aPv[5], bAv[5];
        #pragma unroll
        for (int k = 0; k < 5; ++k) {
            int cc = cc0 + k;
            if (cc > NCHUNK - 1) cc = NCHUNK - 1;
            size_t o = ((size_t)(bb * NCHUNK + cc) * D_INNER + d) * D_STATE + q * 2;
            aPv[k] = *(const float2*)(aPbuf + o);
            bAv[k] = *(const float2*)(bAbuf + o);
        }
        #pragma unroll
        for (int k = 0; k < 5; ++k) {
            if (cc0 + k < c) {
                h0 = h0 * aPv[k].x + bAv[k].x;
                h1 = h1 * aPv[k].y + bAv[k].y;
            }
        }
    }

    size_t rbase = (size_t)bb * LSEQ + (size_t)c * TCH;
    const float4* pdt = (const float4*)(dtT + (size_t)d * NROWS + rbase);
    const float4* pxc = (const float4*)(xcT + (size_t)d * NROWS + rbase);
    const float4* pb0 = (const float4*)(bcT + (size_t)(2 * q + 0) * NROWS + rbase);
    const float4* pb1 = (const float4*)(bcT + (size_t)(2 * q + 1) * NROWS + rbase);
    const float4* pc0 = (const float4*)(bcT + (size_t)(16 + 2 * q) * NROWS + rbase);
    const float4* pc1 = (const float4*)(bcT + (size_t)(17 + 2 * q) * NROWS + rbase);
    const float4* pz  = (const float4*)(xzT + (size_t)(D_INNER + d) * NROWS + rbase);
    unsigned short* py = y + rbase * D_INNER + d;

    float4 dt4 = pdt[0], xc4 = pxc[0];
    float4 b04 = pb0[0], b14 = pb1[0], c04 = pc0[0], c14 = pc1[0];
    float4 z4 = make_float4(0.f, 0.f, 0.f, 0.f);
    if (q == 0) z4 = pz[0];

    for (int g = 0; g < TCH / 4; ++g) {
        int gn = (g + 1 < TCH / 4) ? g + 1 : g;
        float4 dtn = pdt[gn], xcn = pxc[gn];
        float4 b0n = pb0[gn], b1n = pb1[gn], c0n = pc0[gn], c1n = pc1[gn];
        float4 zn = z4;
        if (q == 0) zn = pz[gn];

        #define P2STEP(F, KOFF) { \
            float dtv = dt4.F, dx = dt4.F * xc4.F; \
            float a0 = __expf(dtv * A0); h0 = h0 * a0 + dx * b04.F; \
            float a1 = __expf(dtv * A1); h1 = h1 * a1 + dx * b14.F; \
            float p = h0 * c04.F + h1 * c14.F; \
            p += __shfl_xor(p, 1, 8); \
            p += __shfl_xor(p, 2, 8); \
            p += __shfl_xor(p, 4, 8); \
            if (q == 0) { \
                float zv = z4.F; \
                float sz = zv / (1.f + __expf(-zv)); \
                py[(size_t)(4 * g + KOFF) * D_INNER] = \
                    (unsigned short)bfbits((p + xc4.F * Dd) * sz); \
            } }
        P2STEP(x, 0) P2STEP(y, 1) P2STEP(z, 2) P2STEP(w, 3)
        #undef P2STEP

        dt4 = dtn; xc4 = xcn; b04 = b0n; b14 = b1n; c04 = c0n; c14 = c1n; z4 = zn;
    }
}

// ---------------------------------------------------------------------------
extern "C" void kernel_launch(void* const* d_in, const int* in_sizes, int n_in,
                              void* d_out, int out_size, void* d_ws, size_t ws_size,
                              hipStream_t stream)
{
    const float* h_in  = (const float*)d_in[0];
    const float* iw    = (const float*)d_in[1];   // (4, 4096, 1024)
    const float* cw    = (const float*)d_in[2];   // (4, 2048, 4)
    const float* cb    = (const float*)d_in[3];   // (4, 2048)
    const float* xw    = (const float*)d_in[4];   // (4, 96, 2048)
    const float* dw    = (const float*)d_in[5];   // (4, 2048, 64)
    const float* db    = (const float*)d_in[6];   // (4, 2048)
    const float* Alog  = (const float*)d_in[7];   // (4, 2048, 16)
    const float* Dp    = (const float*)d_in[8];   // (4, 2048)
    const float* ow    = (const float*)d_in[9];   // (4, 1024, 2048)
    const float* nw    = (const float*)d_in[10];  // (4, 1024)
    const float* nb    = (const float*)d_in[11];  // (4, 1024)
    const float* nfw   = (const float*)d_in[12];  // (1024,)
    const float* nfb   = (const float*)d_in[13];  // (1024,)

    // workspace layout — identical total (25,362,432 floats)
    float* ws = (float*)d_ws;
    float* residual = ws;                       // 2,097,152
    float* hs       = residual + 2097152;       // 2,097,152 (aP/bA + out_proj out)
    float* xzT      = hs + 2097152;             // 8,388,608  [e=4096][r=2048]
    float* xcT      = xzT + 8388608;            // 4,194,304  [d=2048][r=2048]
    float* dtT      = xcT + 4194304;            // 4,194,304  [d=2048][r=2048]
    float* dbl      = dtT + 4194304;            // 196,608    [m=2048][96]
    float* y        = dbl + 196608;             // 4,194,304

    // chunk transfer buffers alias hs (dead between add_ln-consume and out_proj)
    float* aPbuf = hs;
    float* bAbuf = hs + 1048576;

    // bf16 staging + bcT, all in dead/free regions:
    //  - wbuf_in  (in_proj w bf16, 2M floats)  -> y[0 .. 2M)
    //  - hs_bf16  (LN out bf16,   1M floats)   -> y[2M .. 3M)
    //  - y_bf16   (scan out bf16, 2M floats)   -> y[0 .. 2M)
    //  - bcT      (B/C transposed, 64K floats) -> y[3M .. 3M+64K)  (always free)
    //  - wbuf_out (out_proj w bf16, 1M floats) -> dtT[0 .. 1M) (dead after scan)
    unsigned short* wbuf_in  = (unsigned short*)y;
    unsigned short* hs_bf16  = (unsigned short*)(y + 2097152);
    unsigned short* y_bf16   = (unsigned short*)y;
    float*          bcT      = y + 3145728;
    unsigned short* wbuf_out = (unsigned short*)dtT;

    const float* cur_add = h_in;
    for (int i = 0; i < N_LAYER; ++i) {
        // residual add + LN, emit bf16
        add_ln_kernel<<<NROWS, 256, 0, stream>>>(cur_add, residual,
                                                 nw + i * D_MODEL, nb + i * D_MODEL,
                                                 hs_bf16, i == 0, 1);
        // convert in_proj weights -> bf16 (dead y space)
        f32_to_bf16_kernel<<<(2 * D_INNER * D_MODEL) / 1024, 256, 0, stream>>>(
            iw + (size_t)i * 2 * D_INNER * D_MODEL, wbuf_in);
        // in_proj (bf16 MFMA), TRANSPOSED out: xzT[e][r]
        gemm_bf16_nt<<<dim3(2 * D_INNER / BBN, NROWS / BBM), 256, 0, stream>>>(
            hs_bf16, wbuf_in, xzT, NROWS, 2 * D_INNER, D_MODEL, 1);
        // conv + silu (t-contiguous): xzT x-rows -> xcT
        conv_silu_kernel<<<(D_INNER * NROWS / 4) / 256, 256, 0, stream>>>(
            xzT, cw + (size_t)i * D_INNER * D_CONV, cb + i * D_INNER, xcT);
        // x_proj (fp32 split-K x8, A transposed): xcT -> dbl [m][96]
        hipMemsetAsync(dbl, 0, 196608 * sizeof(float), stream);
        gemm_tn_splitk<<<dim3(2, NROWS / TILE, 8), 256, 0, stream>>>(
            xcT, xw + (size_t)i * 96 * D_INNER, dbl,
            NROWS, 96, D_INNER, NROWS, D_INNER, 96, D_INNER / 8);
        // dt_proj + softplus, TRANSPOSED out: dtT[d][r]
        gemm_nt<<<dim3(D_INNER / TILE, NROWS / TILE), 256, 0, stream>>>(
            dbl, dw + (size_t)i * D_INNER * DT_RANK, dtT,
            NROWS, D_INNER, DT_RANK, 96, DT_RANK, NROWS, db + i * D_INNER, 1, 1);
        // transpose B/C cols of dbl -> bcT [32][r]
        transpose_bc<<<NROWS / 64, 256, 0, stream>>>(dbl, bcT);
        // chunked selective scan (all t-contiguous operands)
        scan_pass1<<<NB * NCHUNK * (D_INNER / 32), 256, 0, stream>>>(
            dtT, xcT, bcT, Alog + (size_t)i * D_INNER * D_STATE, aPbuf, bAbuf);
        scan_pass2<<<NB * NCHUNK * (D_INNER / 32), 256, 0, stream>>>(
            dtT, xcT, bcT, xzT, Alog + (size_t)i * D_INNER * D_STATE, Dp + i * D_INNER,
            aPbuf, bAbuf, y_bf16);
        // convert out_proj weights -> bf16 (dead dtT space)
        f32_to_bf16_kernel<<<(D_MODEL * D_INNER) / 1024, 256, 0, stream>>>(
            ow + (size_t)i * D_MODEL * D_INNER, wbuf_out);
        // out_proj (bf16 MFMA), normal layout out: hs [r][1024]
        gemm_bf16_nt<<<dim3(D_MODEL / BBN, NROWS / BBM), 256, 0, stream>>>(
            y_bf16, wbuf_out, hs, NROWS, D_MODEL, D_INNER, 0);
        cur_add = hs;
    }
    add_ln_kernel<<<NROWS, 256, 0, stream>>>(hs, residual, nfw, nfb, d_out, 0, 0);
}

// Round 5
// 1142.971 us; speedup vs baseline: 1.1324x; 1.1324x over previous
//
#include <hip/hip_runtime.h>
#include <math.h>

#define D_MODEL 1024
#define D_INNER 2048
#define D_STATE 16
#define D_CONV  4
#define DT_RANK 64
#define NB      2
#define LSEQ    1024
#define NROWS   (NB * LSEQ)   // 2048
#define LN_EPS  1e-5f
#define N_LAYER 4
#define NCHUNK  32
#define TCH     (LSEQ / NCHUNK)   // 32 steps per chunk

__device__ inline unsigned bfbits(float f) {
    unsigned u = __float_as_uint(f);
    return (u + 0x7fffu + ((u >> 16) & 1u)) >> 16;  // RNE
}

// ---------------------------------------------------------------------------
// Fused residual-add + LayerNorm. bf16out=1: emit bf16; 0: fp32.
// ---------------------------------------------------------------------------
__device__ inline float wave_sum(float s) {
    #pragma unroll
    for (int m = 1; m < 64; m <<= 1) s += __shfl_xor(s, m, 64);
    return s;
}

__global__ __launch_bounds__(256)
void add_ln_kernel(const float* __restrict__ add, float* __restrict__ residual,
                   const float* __restrict__ w, const float* __restrict__ b,
                   void* __restrict__ out, int first, int bf16out)
{
    int row = blockIdx.x;
    int tid = threadIdx.x;
    size_t base = (size_t)row * D_MODEL + tid * 4;

    float4 v = *(const float4*)(add + base);
    if (!first) {
        float4 r = *(const float4*)(residual + base);
        v.x += r.x; v.y += r.y; v.z += r.z; v.w += r.w;
    }
    *(float4*)(residual + base) = v;

    __shared__ float red[8];
    float s = v.x + v.y + v.z + v.w;
    s = wave_sum(s);
    if ((tid & 63) == 0) red[tid >> 6] = s;
    __syncthreads();
    float mu = (red[0] + red[1] + red[2] + red[3]) * (1.0f / D_MODEL);

    float dx = v.x - mu, dy = v.y - mu, dz = v.z - mu, dw2 = v.w - mu;
    float s2 = dx*dx + dy*dy + dz*dz + dw2*dw2;
    s2 = wave_sum(s2);
    if ((tid & 63) == 0) red[4 + (tid >> 6)] = s2;
    __syncthreads();
    float var = (red[4] + red[5] + red[6] + red[7]) * (1.0f / D_MODEL);
    float rs = rsqrtf(var + LN_EPS);

    float4 wv = *(const float4*)(w + tid * 4);
    float4 bv = *(const float4*)(b + tid * 4);
    float4 o;
    o.x = dx  * rs * wv.x + bv.x;
    o.y = dy  * rs * wv.y + bv.y;
    o.z = dz  * rs * wv.z + bv.z;
    o.w = dw2 * rs * wv.w + bv.w;
    if (bf16out) {
        ushort4 ov;
        ov.x = (unsigned short)bfbits(o.x);
        ov.y = (unsigned short)bfbits(o.y);
        ov.z = (unsigned short)bfbits(o.z);
        ov.w = (unsigned short)bfbits(o.w);
        *(ushort4*)((unsigned short*)out + base) = ov;
    } else {
        *(float4*)((float*)out + base) = o;
    }
}

// ---------------------------------------------------------------------------
// fp32 -> bf16 bulk convert (weights). grid*256*4 must equal element count.
// ---------------------------------------------------------------------------
__global__ __launch_bounds__(256)
void f32_to_bf16_kernel(const float* __restrict__ src, unsigned short* __restrict__ dst)
{
    int i = blockIdx.x * 256 + threadIdx.x;
    float4 v = *(const float4*)(src + (size_t)i * 4);
    ushort4 o;
    o.x = (unsigned short)bfbits(v.x);
    o.y = (unsigned short)bfbits(v.y);
    o.z = (unsigned short)bfbits(v.z);
    o.w = (unsigned short)bfbits(v.w);
    *(ushort4*)(dst + (size_t)i * 4) = o;
}

// ---------------------------------------------------------------------------
// fp32 NT GEMM (dt_proj). 64x64 tile, 4x4/thread. mode 1: softplus(acc+bias).
// ---------------------------------------------------------------------------
#define TILE 64
#define KT   16

__global__ __launch_bounds__(256)
void gemm_nt(const float* __restrict__ A, const float* __restrict__ B,
             float* __restrict__ C, int M, int N, int K,
             int lda, int ldb, int ldc,
             const float* __restrict__ bias, int mode)
{
    __shared__ float As[KT][TILE + 4];
    __shared__ float Bs[KT][TILE + 4];

    int tid = threadIdx.x;
    int tx = tid & 15, ty = tid >> 4;
    int m0 = blockIdx.y * TILE;
    int n0 = blockIdx.x * TILE;

    int lr = tid >> 2;
    int lk = (tid & 3) * 4;

    float acc[4][4] = {};

    for (int k0 = 0; k0 < K; k0 += KT) {
        {
            int m = m0 + lr;
            float4 v = *(const float4*)(A + (size_t)m * lda + k0 + lk);
            As[lk + 0][lr] = v.x; As[lk + 1][lr] = v.y;
            As[lk + 2][lr] = v.z; As[lk + 3][lr] = v.w;
        }
        {
            int n = n0 + lr;
            float4 v = make_float4(0.f, 0.f, 0.f, 0.f);
            if (n < N) v = *(const float4*)(B + (size_t)n * ldb + k0 + lk);
            Bs[lk + 0][lr] = v.x; Bs[lk + 1][lr] = v.y;
            Bs[lk + 2][lr] = v.z; Bs[lk + 3][lr] = v.w;
        }
        __syncthreads();
        #pragma unroll
        for (int kk = 0; kk < KT; ++kk) {
            float4 a4 = *(const float4*)&As[kk][ty * 4];
            float4 b4 = *(const float4*)&Bs[kk][tx * 4];
            float av[4] = {a4.x, a4.y, a4.z, a4.w};
            float bv[4] = {b4.x, b4.y, b4.z, b4.w};
            #pragma unroll
            for (int i = 0; i < 4; ++i)
                #pragma unroll
                for (int j = 0; j < 4; ++j)
                    acc[i][j] += av[i] * bv[j];
        }
        __syncthreads();
    }

    #pragma unroll
    for (int i = 0; i < 4; ++i) {
        int m = m0 + ty * 4 + i;
        #pragma unroll
        for (int j = 0; j < 4; ++j) {
            int n = n0 + tx * 4 + j;
            if (n >= N) continue;
            float v = acc[i][j];
            if (mode == 1) {
                v += bias[n];
                v = (v > 20.f) ? v : log1pf(__expf(v));
            }
            C[(size_t)m * ldc + n] = v;
        }
    }
}

// ---------------------------------------------------------------------------
// fp32 NT GEMM with split-K (x_proj). C pre-zeroed; atomicAdd epilogue.
// ---------------------------------------------------------------------------
__global__ __launch_bounds__(256)
void gemm_nt_splitk(const float* __restrict__ A, const float* __restrict__ B,
                    float* __restrict__ C, int M, int N, int K,
                    int lda, int ldb, int ldc, int kslice)
{
    __shared__ float As[KT][TILE + 4];
    __shared__ float Bs[KT][TILE + 4];

    int tid = threadIdx.x;
    int tx = tid & 15, ty = tid >> 4;
    int m0 = blockIdx.y * TILE;
    int n0 = blockIdx.x * TILE;
    int kb = blockIdx.z * kslice;

    int lr = tid >> 2;
    int lk = (tid & 3) * 4;

    float acc[4][4] = {};

    for (int k0 = kb; k0 < kb + kslice; k0 += KT) {
        {
            int m = m0 + lr;
            float4 v = *(const float4*)(A + (size_t)m * lda + k0 + lk);
            As[lk + 0][lr] = v.x; As[lk + 1][lr] = v.y;
            As[lk + 2][lr] = v.z; As[lk + 3][lr] = v.w;
        }
        {
            int n = n0 + lr;
            float4 v = make_float4(0.f, 0.f, 0.f, 0.f);
            if (n < N) v = *(const float4*)(B + (size_t)n * ldb + k0 + lk);
            Bs[lk + 0][lr] = v.x; Bs[lk + 1][lr] = v.y;
            Bs[lk + 2][lr] = v.z; Bs[lk + 3][lr] = v.w;
        }
        __syncthreads();
        #pragma unroll
        for (int kk = 0; kk < KT; ++kk) {
            float4 a4 = *(const float4*)&As[kk][ty * 4];
            float4 b4 = *(const float4*)&Bs[kk][tx * 4];
            float av[4] = {a4.x, a4.y, a4.z, a4.w};
            float bv[4] = {b4.x, b4.y, b4.z, b4.w};
            #pragma unroll
            for (int i = 0; i < 4; ++i)
                #pragma unroll
                for (int j = 0; j < 4; ++j)
                    acc[i][j] += av[i] * bv[j];
        }
        __syncthreads();
    }

    #pragma unroll
    for (int i = 0; i < 4; ++i) {
        int m = m0 + ty * 4 + i;
        #pragma unroll
        for (int j = 0; j < 4; ++j) {
            int n = n0 + tx * 4 + j;
            if (n < N) atomicAdd(&C[(size_t)m * ldc + n], acc[i][j]);
        }
    }
}

// ---------------------------------------------------------------------------
// bf16 MFMA NT GEMM — both operands pre-converted bf16 (uint4 passthrough
// staging). 128x128 tile, BK=64, 4 waves, mfma_f32_16x16x32_bf16, LDS_S=72.
// ---------------------------------------------------------------------------
using bf16x8 = __attribute__((ext_vector_type(8))) short;
using f32x4  = __attribute__((ext_vector_type(4))) float;

#define BBM 128
#define BBN 128
#define BBK 64
#define LDS_S (BBK + 8)   // 72 bf16 -> 144B row stride

__global__ __launch_bounds__(256)
void gemm_bf16_nt(const unsigned short* __restrict__ A, const unsigned short* __restrict__ Bw,
                  float* __restrict__ C, int M, int N, int K)
{
    __shared__ unsigned short As[BBM * LDS_S];
    __shared__ unsigned short Bs[BBN * LDS_S];

    int tid = threadIdx.x;
    int m0 = blockIdx.y * BBM, n0 = blockIdx.x * BBN;
    int lane = tid & 63, w = tid >> 6;
    int wm = (w >> 1) * 64, wn = (w & 1) * 64;
    int lm = lane & 15, q = lane >> 4;

    int lr = tid >> 3;          // 0..31  (staging row)
    int lc = (tid & 7) * 8;     // 0..56  (staging col, bf16 elems)

    f32x4 acc[4][4] = {};

    for (int k0 = 0; k0 < K; k0 += BBK) {
        #pragma unroll
        for (int r = 0; r < 4; ++r) {
            int row = lr + r * 32;
            uint4 av = *(const uint4*)(A + (size_t)(m0 + row) * K + k0 + lc);
            *(uint4*)&As[row * LDS_S + lc] = av;
        }
        #pragma unroll
        for (int r = 0; r < 4; ++r) {
            int row = lr + r * 32;
            uint4 pv = *(const uint4*)(Bw + (size_t)(n0 + row) * K + k0 + lc);
            *(uint4*)&Bs[row * LDS_S + lc] = pv;
        }
        __syncthreads();
        #pragma unroll
        for (int kk = 0; kk < BBK; kk += 32) {
            bf16x8 af[4], bf[4];
            #pragma unroll
            for (int i = 0; i < 4; ++i)
                af[i] = *(const bf16x8*)&As[(wm + i * 16 + lm) * LDS_S + kk + q * 8];
            #pragma unroll
            for (int j = 0; j < 4; ++j)
                bf[j] = *(const bf16x8*)&Bs[(wn + j * 16 + lm) * LDS_S + kk + q * 8];
            #pragma unroll
            for (int i = 0; i < 4; ++i)
                #pragma unroll
                for (int j = 0; j < 4; ++j)
                    acc[i][j] = __builtin_amdgcn_mfma_f32_16x16x32_bf16(
                        af[i], bf[j], acc[i][j], 0, 0, 0);
        }
        __syncthreads();
    }

    #pragma unroll
    for (int i = 0; i < 4; ++i)
        #pragma unroll
        for (int j = 0; j < 4; ++j)
            #pragma unroll
            for (int r = 0; r < 4; ++r) {
                int row = m0 + wm + i * 16 + q * 4 + r;
                int col = n0 + wn + j * 16 + lm;
                C[(size_t)row * N + col] = acc[i][j][r];
            }
}

// ---------------------------------------------------------------------------
// Depthwise causal conv (width 4) + bias + SiLU (r3-proven interleaved form).
// ---------------------------------------------------------------------------
__global__ __launch_bounds__(256)
void conv_silu_kernel(const float* __restrict__ xz, const float* __restrict__ cw,
                      const float* __restrict__ cb, float* __restrict__ xc)
{
    int idx = blockIdx.x * 256 + threadIdx.x;
    int d  = idx & (D_INNER - 1);
    int t  = (idx >> 11) & (LSEQ - 1);
    int bb = idx >> 21;

    const float* xcol = xz + (size_t)bb * LSEQ * 2 * D_INNER + d;
    float acc = cb[d];
    #pragma unroll
    for (int k = 0; k < D_CONV; ++k) {
        int tt = t + k - (D_CONV - 1);
        if (tt >= 0) acc += xcol[(size_t)tt * 2 * D_INNER] * cw[d * D_CONV + k];
    }
    acc = acc / (1.f + __expf(-acc));
    xc[idx] = acc;
}

// ---------------------------------------------------------------------------
// Chunked selective scan, v5: ONE LANE PER d — all 16 states in registers.
// No cross-lane shuffles; B/C loads are wave-uniform (one line per wave).
// NCHUNK=32 -> 2048 waves (2/SIMD). Interleaved [r][d] operand layout
// (r3-proven cache behavior). 1-step lookahead prefetch.
// ---------------------------------------------------------------------------
#define UNPK4(dst, off, v) { dst[(off)+0]=(v).x; dst[(off)+1]=(v).y; \
                             dst[(off)+2]=(v).z; dst[(off)+3]=(v).w; }

__global__ __launch_bounds__(256)
void scan_pass1(const float* __restrict__ dtb, const float* __restrict__ xc,
                const float* __restrict__ dbl, const float* __restrict__ Alog,
                float* __restrict__ aPbuf, float* __restrict__ bAbuf)
{
    int tid = threadIdx.x;
    int blk = blockIdx.x;            // grid = NB * NCHUNK * (D_INNER/256) = 512
    int dg  = blk & 7;
    int c   = (blk >> 3) & (NCHUNK - 1);
    int bb  = blk >> 8;
    int d   = dg * 256 + tid;

    float A[16];
    #pragma unroll
    for (int s = 0; s < 16; s += 4) {
        float4 v = *(const float4*)(Alog + (size_t)d * D_STATE + s);
        A[s+0] = -__expf(v.x); A[s+1] = -__expf(v.y);
        A[s+2] = -__expf(v.z); A[s+3] = -__expf(v.w);
    }

    size_t rowbase = (size_t)bb * LSEQ + (size_t)c * TCH;
    const float* pdt = dtb + rowbase * D_INNER + d;
    const float* pxc = xc  + rowbase * D_INNER + d;
    const float* pbc = dbl + rowbase * 96 + DT_RANK;   // wave-uniform address

    float aP[16], bA[16];
    #pragma unroll
    for (int s = 0; s < 16; ++s) { aP[s] = 1.f; bA[s] = 0.f; }

    float dt = pdt[0], xv = pxc[0];
    float4 B0 = *(const float4*)(pbc + 0);
    float4 B1 = *(const float4*)(pbc + 4);
    float4 B2 = *(const float4*)(pbc + 8);
    float4 B3 = *(const float4*)(pbc + 12);

    for (int t = 0; t < TCH; ++t) {
        int tn = (t + 1 < TCH) ? t + 1 : t;
        size_t rn = (size_t)tn * D_INNER;
        float dt_n = pdt[rn], xv_n = pxc[rn];
        const float* pn = pbc + (size_t)tn * 96;
        float4 B0n = *(const float4*)(pn + 0);
        float4 B1n = *(const float4*)(pn + 4);
        float4 B2n = *(const float4*)(pn + 8);
        float4 B3n = *(const float4*)(pn + 12);

        float B[16];
        UNPK4(B, 0, B0) UNPK4(B, 4, B1) UNPK4(B, 8, B2) UNPK4(B, 12, B3)
        float dtx = dt * xv;
        #pragma unroll
        for (int s = 0; s < 16; ++s) {
            float a = __expf(dt * A[s]);
            aP[s] *= a;
            bA[s] = bA[s] * a + dtx * B[s];
        }
        dt = dt_n; xv = xv_n; B0 = B0n; B1 = B1n; B2 = B2n; B3 = B3n;
    }

    float* pa = aPbuf + ((size_t)(bb * NCHUNK + c) * D_INNER + d) * D_STATE;
    float* pb = bAbuf + ((size_t)(bb * NCHUNK + c) * D_INNER + d) * D_STATE;
    #pragma unroll
    for (int s = 0; s < 16; s += 4) {
        *(float4*)(pa + s) = make_float4(aP[s], aP[s+1], aP[s+2], aP[s+3]);
        *(float4*)(pb + s) = make_float4(bA[s], bA[s+1], bA[s+2], bA[s+3]);
    }
}

__global__ __launch_bounds__(256)
void scan_pass2(const float* __restrict__ dtb, const float* __restrict__ xc,
                const float* __restrict__ dbl, const float* __restrict__ xz,
                const float* __restrict__ Alog, const float* __restrict__ Dp,
                const float* __restrict__ aPbuf, const float* __restrict__ bAbuf,
                unsigned short* __restrict__ y)
{
    int tid = threadIdx.x;
    int blk = blockIdx.x;
    int dg  = blk & 7;
    int c   = (blk >> 3) & (NCHUNK - 1);
    int bb  = blk >> 8;
    int d   = dg * 256 + tid;

    float A[16];
    #pragma unroll
    for (int s = 0; s < 16; s += 4) {
        float4 v = *(const float4*)(Alog + (size_t)d * D_STATE + s);
        A[s+0] = -__expf(v.x); A[s+1] = -__expf(v.y);
        A[s+2] = -__expf(v.z); A[s+3] = -__expf(v.w);
    }
    float Dd = Dp[d];

    float h[16];
    #pragma unroll
    for (int s = 0; s < 16; ++s) h[s] = 0.f;

    // prefix compose over chunks [0, c)
    for (int cc = 0; cc < c; ++cc) {
        const float* pa = aPbuf + ((size_t)(bb * NCHUNK + cc) * D_INNER + d) * D_STATE;
        const float* pb = bAbuf + ((size_t)(bb * NCHUNK + cc) * D_INNER + d) * D_STATE;
        float4 a0 = *(const float4*)(pa + 0),  a1 = *(const float4*)(pa + 4);
        float4 a2 = *(const float4*)(pa + 8),  a3 = *(const float4*)(pa + 12);
        float4 b0 = *(const float4*)(pb + 0),  b1 = *(const float4*)(pb + 4);
        float4 b2 = *(const float4*)(pb + 8),  b3 = *(const float4*)(pb + 12);
        float av[16], bv[16];
        UNPK4(av, 0, a0) UNPK4(av, 4, a1) UNPK4(av, 8, a2) UNPK4(av, 12, a3)
        UNPK4(bv, 0, b0) UNPK4(bv, 4, b1) UNPK4(bv, 8, b2) UNPK4(bv, 12, b3)
        #pragma unroll
        for (int s = 0; s < 16; ++s) h[s] = h[s] * av[s] + bv[s];
    }

    size_t rowbase = (size_t)bb * LSEQ + (size_t)c * TCH;
    const float* pdt = dtb + rowbase * D_INNER + d;
    const float* pxc = xc  + rowbase * D_INNER + d;
    const float* pz  = xz  + rowbase * 2 * D_INNER + D_INNER + d;
    const float* pbc = dbl + rowbase * 96 + DT_RANK;   // wave-uniform address
    unsigned short* py = y + rowbase * D_INNER + d;

    float dt = pdt[0], xv = pxc[0], zv = pz[0];
    float4 B0 = *(const float4*)(pbc + 0);
    float4 B1 = *(const float4*)(pbc + 4);
    float4 B2 = *(const float4*)(pbc + 8);
    float4 B3 = *(const float4*)(pbc + 12);
    float4 C0 = *(const float4*)(pbc + 16);
    float4 C1 = *(const float4*)(pbc + 20);
    float4 C2 = *(const float4*)(pbc + 24);
    float4 C3 = *(const float4*)(pbc + 28);

    for (int t = 0; t < TCH; ++t) {
        int tn = (t + 1 < TCH) ? t + 1 : t;
        size_t rn = (size_t)tn * D_INNER;
        float dt_n = pdt[rn], xv_n = pxc[rn], zv_n = pz[2 * rn];
        const float* pn = pbc + (size_t)tn * 96;
        float4 B0n = *(const float4*)(pn + 0);
        float4 B1n = *(const float4*)(pn + 4);
        float4 B2n = *(const float4*)(pn + 8);
        float4 B3n = *(const float4*)(pn + 12);
        float4 C0n = *(const float4*)(pn + 16);
        float4 C1n = *(const float4*)(pn + 20);
        float4 C2n = *(const float4*)(pn + 24);
        float4 C3n = *(const float4*)(pn + 28);

        float B[16], C[16];
        UNPK4(B, 0, B0) UNPK4(B, 4, B1) UNPK4(B, 8, B2) UNPK4(B, 12, B3)
        UNPK4(C, 0, C0) UNPK4(C, 4, C1) UNPK4(C, 8, C2) UNPK4(C, 12, C3)

        float dtx = dt * xv;
        float p0 = 0.f, p1 = 0.f, p2 = 0.f, p3 = 0.f;
        #pragma unroll
        for (int s = 0; s < 16; s += 4) {
            float a;
            a = __expf(dt * A[s+0]); h[s+0] = h[s+0] * a + dtx * B[s+0]; p0 += h[s+0] * C[s+0];
            a = __expf(dt * A[s+1]); h[s+1] = h[s+1] * a + dtx * B[s+1]; p1 += h[s+1] * C[s+1];
            a = __expf(dt * A[s+2]); h[s+2] = h[s+2] * a + dtx * B[s+2]; p2 += h[s+2] * C[s+2];
            a = __expf(dt * A[s+3]); h[s+3] = h[s+3] * a + dtx * B[s+3]; p3 += h[s+3] * C[s+3];
        }
        float p = (p0 + p1) + (p2 + p3);
        float sz = zv / (1.f + __expf(-zv));
        py[(size_t)t * D_INNER] = (unsigned short)bfbits((p + xv * Dd) * sz);

        dt = dt_n; xv = xv_n; zv = zv_n;
        B0 = B0n; B1 = B1n; B2 = B2n; B3 = B3n;
        C0 = C0n; C1 = C1n; C2 = C2n; C3 = C3n;
    }
}

// ---------------------------------------------------------------------------
extern "C" void kernel_launch(void* const* d_in, const int* in_sizes, int n_in,
                              void* d_out, int out_size, void* d_ws, size_t ws_size,
                              hipStream_t stream)
{
    const float* h_in  = (const float*)d_in[0];
    const float* iw    = (const float*)d_in[1];   // (4, 4096, 1024)
    const float* cw    = (const float*)d_in[2];   // (4, 2048, 4)
    const float* cb    = (const float*)d_in[3];   // (4, 2048)
    const float* xw    = (const float*)d_in[4];   // (4, 96, 2048)
    const float* dw    = (const float*)d_in[5];   // (4, 2048, 64)
    const float* db    = (const float*)d_in[6];   // (4, 2048)
    const float* Alog  = (const float*)d_in[7];   // (4, 2048, 16)
    const float* Dp    = (const float*)d_in[8];   // (4, 2048)
    const float* ow    = (const float*)d_in[9];   // (4, 1024, 2048)
    const float* nw    = (const float*)d_in[10];  // (4, 1024)
    const float* nb    = (const float*)d_in[11];  // (4, 1024)
    const float* nfw   = (const float*)d_in[12];  // (1024,)
    const float* nfb   = (const float*)d_in[13];  // (1024,)

    // workspace layout — identical total (25,362,432 floats)
    float* ws = (float*)d_ws;
    float* residual = ws;                       // 2,097,152
    float* hs       = residual + 2097152;       // 2,097,152 (aPbuf + out_proj out)
    float* xz       = hs + 2097152;             // 8,388,608  [r][4096]
    float* xc       = xz + 8388608;             // 4,194,304  [r][2048]
    float* dtb      = xc + 4194304;             // 4,194,304  [r][2048]
    float* dbl      = dtb + 4194304;            // 196,608    [r][96]
    float* y        = dbl + 196608;             // 4,194,304

    // aPbuf (2M floats) aliases hs (dead between in_proj-consume and out_proj).
    // bAbuf (2M floats) lives in y[2M..4M) — free during scan (hs_bf16 there is
    // dead after in_proj; bcT no longer exists).
    float* aPbuf = hs;
    float* bAbuf = y + 2097152;

    // bf16 staging in dead regions:
    //  - wbuf_in  (in_proj w bf16, 2M floats)  -> y[0 .. 2M)
    //  - hs_bf16  (LN out bf16,   1M floats)   -> y[2M .. 3M) (dead before scan)
    //  - y_bf16   (scan out bf16, 2M floats)   -> y[0 .. 2M)
    //  - wbuf_out (out_proj w bf16, 1M floats) -> dtb[0 .. 1M) (dead after scan)
    unsigned short* wbuf_in  = (unsigned short*)y;
    unsigned short* hs_bf16  = (unsigned short*)(y + 2097152);
    unsigned short* y_bf16   = (unsigned short*)y;
    unsigned short* wbuf_out = (unsigned short*)dtb;

    const float* cur_add = h_in;
    for (int i = 0; i < N_LAYER; ++i) {
        // residual add + LN, emit bf16
        add_ln_kernel<<<NROWS, 256, 0, stream>>>(cur_add, residual,
                                                 nw + i * D_MODEL, nb + i * D_MODEL,
                                                 hs_bf16, i == 0, 1);
        // convert in_proj weights -> bf16 (dead y space)
        f32_to_bf16_kernel<<<(2 * D_INNER * D_MODEL) / 1024, 256, 0, stream>>>(
            iw + (size_t)i * 2 * D_INNER * D_MODEL, wbuf_in);
        // in_proj (bf16 MFMA): -> xz [r][4096] fp32
        gemm_bf16_nt<<<dim3(2 * D_INNER / BBN, NROWS / BBM), 256, 0, stream>>>(
            hs_bf16, wbuf_in, xz, NROWS, 2 * D_INNER, D_MODEL);
        // conv + silu -> xc [r][2048]
        conv_silu_kernel<<<NB * LSEQ * D_INNER / 256, 256, 0, stream>>>(
            xz, cw + (size_t)i * D_INNER * D_CONV, cb + i * D_INNER, xc);
        // x_proj (fp32 split-K x8): -> dbl [r][96]
        hipMemsetAsync(dbl, 0, 196608 * sizeof(float), stream);
        gemm_nt_splitk<<<dim3(2, NROWS / TILE, 8), 256, 0, stream>>>(
            xc, xw + (size_t)i * 96 * D_INNER, dbl,
            NROWS, 96, D_INNER, D_INNER, D_INNER, 96, D_INNER / 8);
        // dt_proj + softplus: -> dtb [r][2048]
        gemm_nt<<<dim3(D_INNER / TILE, NROWS / TILE), 256, 0, stream>>>(
            dbl, dw + (size_t)i * D_INNER * DT_RANK, dtb,
            NROWS, D_INNER, DT_RANK, 96, DT_RANK, D_INNER, db + i * D_INNER, 1);
        // chunked selective scan — 1 lane per d, 16 states in regs, NCHUNK=32
        scan_pass1<<<NB * NCHUNK * (D_INNER / 256), 256, 0, stream>>>(
            dtb, xc, dbl, Alog + (size_t)i * D_INNER * D_STATE, aPbuf, bAbuf);
        scan_pass2<<<NB * NCHUNK * (D_INNER / 256), 256, 0, stream>>>(
            dtb, xc, dbl, xz, Alog + (size_t)i * D_INNER * D_STATE, Dp + i * D_INNER,
            aPbuf, bAbuf, y_bf16);
        // convert out_proj weights -> bf16 (dead dtb space)
        f32_to_bf16_kernel<<<(D_MODEL * D_INNER) / 1024, 256, 0, stream>>>(
            ow + (size_t)i * D_MODEL * D_INNER, wbuf_out);
        // out_proj (bf16 MFMA): -> hs [r][1024] fp32
        gemm_bf16_nt<<<dim3(D_MODEL / BBN, NROWS / BBM), 256, 0, stream>>>(
            y_bf16, wbuf_out, hs, NROWS, D_MODEL, D_INNER);
        cur_add = hs;
    }
    add_ln_kernel<<<NROWS, 256, 0, stream>>>(hs, residual, nfw, nfb, d_out, 0, 0);
}

// Round 6
// 1049.626 us; speedup vs baseline: 1.2331x; 1.0889x over previous
//
#include <hip/hip_runtime.h>
#include <math.h>

#define D_MODEL 1024
#define D_INNER 2048
#define D_STATE 16
#define D_CONV  4
#define DT_RANK 64
#define NB      2
#define LSEQ    1024
#define NROWS   (NB * LSEQ)   // 2048
#define LN_EPS  1e-5f
#define N_LAYER 4
#define NCHUNK  32
#define TCH     (LSEQ / NCHUNK)   // 32 steps per chunk

__device__ inline unsigned bfbits(float f) {
    unsigned u = __float_as_uint(f);
    return (u + 0x7fffu + ((u >> 16) & 1u)) >> 16;  // RNE
}

// ---------------------------------------------------------------------------
// Fused residual-add + LayerNorm. bf16out=1: emit bf16; 0: fp32.
// ---------------------------------------------------------------------------
__device__ inline float wave_sum(float s) {
    #pragma unroll
    for (int m = 1; m < 64; m <<= 1) s += __shfl_xor(s, m, 64);
    return s;
}

__global__ __launch_bounds__(256)
void add_ln_kernel(const float* __restrict__ add, float* __restrict__ residual,
                   const float* __restrict__ w, const float* __restrict__ b,
                   void* __restrict__ out, int first, int bf16out)
{
    int row = blockIdx.x;
    int tid = threadIdx.x;
    size_t base = (size_t)row * D_MODEL + tid * 4;

    float4 v = *(const float4*)(add + base);
    if (!first) {
        float4 r = *(const float4*)(residual + base);
        v.x += r.x; v.y += r.y; v.z += r.z; v.w += r.w;
    }
    *(float4*)(residual + base) = v;

    __shared__ float red[8];
    float s = v.x + v.y + v.z + v.w;
    s = wave_sum(s);
    if ((tid & 63) == 0) red[tid >> 6] = s;
    __syncthreads();
    float mu = (red[0] + red[1] + red[2] + red[3]) * (1.0f / D_MODEL);

    float dx = v.x - mu, dy = v.y - mu, dz = v.z - mu, dw2 = v.w - mu;
    float s2 = dx*dx + dy*dy + dz*dz + dw2*dw2;
    s2 = wave_sum(s2);
    if ((tid & 63) == 0) red[4 + (tid >> 6)] = s2;
    __syncthreads();
    float var = (red[4] + red[5] + red[6] + red[7]) * (1.0f / D_MODEL);
    float rs = rsqrtf(var + LN_EPS);

    float4 wv = *(const float4*)(w + tid * 4);
    float4 bv = *(const float4*)(b + tid * 4);
    float4 o;
    o.x = dx  * rs * wv.x + bv.x;
    o.y = dy  * rs * wv.y + bv.y;
    o.z = dz  * rs * wv.z + bv.z;
    o.w = dw2 * rs * wv.w + bv.w;
    if (bf16out) {
        ushort4 ov;
        ov.x = (unsigned short)bfbits(o.x);
        ov.y = (unsigned short)bfbits(o.y);
        ov.z = (unsigned short)bfbits(o.z);
        ov.w = (unsigned short)bfbits(o.w);
        *(ushort4*)((unsigned short*)out + base) = ov;
    } else {
        *(float4*)((float*)out + base) = o;
    }
}

// ---------------------------------------------------------------------------
// fp32 -> bf16 bulk convert (weights). grid*256*4 must equal element count.
// ---------------------------------------------------------------------------
__global__ __launch_bounds__(256)
void f32_to_bf16_kernel(const float* __restrict__ src, unsigned short* __restrict__ dst)
{
    int i = blockIdx.x * 256 + threadIdx.x;
    float4 v = *(const float4*)(src + (size_t)i * 4);
    ushort4 o;
    o.x = (unsigned short)bfbits(v.x);
    o.y = (unsigned short)bfbits(v.y);
    o.z = (unsigned short)bfbits(v.z);
    o.w = (unsigned short)bfbits(v.w);
    *(ushort4*)(dst + (size_t)i * 4) = o;
}

// ---------------------------------------------------------------------------
// fp32 NT GEMM (dt_proj). 64x64 tile, 4x4/thread. mode 1: softplus(acc+bias).
// ---------------------------------------------------------------------------
#define TILE 64
#define KT   16

__global__ __launch_bounds__(256)
void gemm_nt(const float* __restrict__ A, const float* __restrict__ B,
             float* __restrict__ C, int M, int N, int K,
             int lda, int ldb, int ldc,
             const float* __restrict__ bias, int mode)
{
    __shared__ float As[KT][TILE + 4];
    __shared__ float Bs[KT][TILE + 4];

    int tid = threadIdx.x;
    int tx = tid & 15, ty = tid >> 4;
    int m0 = blockIdx.y * TILE;
    int n0 = blockIdx.x * TILE;

    int lr = tid >> 2;
    int lk = (tid & 3) * 4;

    float acc[4][4] = {};

    for (int k0 = 0; k0 < K; k0 += KT) {
        {
            int m = m0 + lr;
            float4 v = *(const float4*)(A + (size_t)m * lda + k0 + lk);
            As[lk + 0][lr] = v.x; As[lk + 1][lr] = v.y;
            As[lk + 2][lr] = v.z; As[lk + 3][lr] = v.w;
        }
        {
            int n = n0 + lr;
            float4 v = make_float4(0.f, 0.f, 0.f, 0.f);
            if (n < N) v = *(const float4*)(B + (size_t)n * ldb + k0 + lk);
            Bs[lk + 0][lr] = v.x; Bs[lk + 1][lr] = v.y;
            Bs[lk + 2][lr] = v.z; Bs[lk + 3][lr] = v.w;
        }
        __syncthreads();
        #pragma unroll
        for (int kk = 0; kk < KT; ++kk) {
            float4 a4 = *(const float4*)&As[kk][ty * 4];
            float4 b4 = *(const float4*)&Bs[kk][tx * 4];
            float av[4] = {a4.x, a4.y, a4.z, a4.w};
            float bv[4] = {b4.x, b4.y, b4.z, b4.w};
            #pragma unroll
            for (int i = 0; i < 4; ++i)
                #pragma unroll
                for (int j = 0; j < 4; ++j)
                    acc[i][j] += av[i] * bv[j];
        }
        __syncthreads();
    }

    #pragma unroll
    for (int i = 0; i < 4; ++i) {
        int m = m0 + ty * 4 + i;
        #pragma unroll
        for (int j = 0; j < 4; ++j) {
            int n = n0 + tx * 4 + j;
            if (n >= N) continue;
            float v = acc[i][j];
            if (mode == 1) {
                v += bias[n];
                v = (v > 20.f) ? v : log1pf(__expf(v));
            }
            C[(size_t)m * ldc + n] = v;
        }
    }
}

// ---------------------------------------------------------------------------
// fp32 NT GEMM with split-K (x_proj). C pre-zeroed; atomicAdd epilogue.
// ---------------------------------------------------------------------------
__global__ __launch_bounds__(256)
void gemm_nt_splitk(const float* __restrict__ A, const float* __restrict__ B,
                    float* __restrict__ C, int M, int N, int K,
                    int lda, int ldb, int ldc, int kslice)
{
    __shared__ float As[KT][TILE + 4];
    __shared__ float Bs[KT][TILE + 4];

    int tid = threadIdx.x;
    int tx = tid & 15, ty = tid >> 4;
    int m0 = blockIdx.y * TILE;
    int n0 = blockIdx.x * TILE;
    int kb = blockIdx.z * kslice;

    int lr = tid >> 2;
    int lk = (tid & 3) * 4;

    float acc[4][4] = {};

    for (int k0 = kb; k0 < kb + kslice; k0 += KT) {
        {
            int m = m0 + lr;
            float4 v = *(const float4*)(A + (size_t)m * lda + k0 + lk);
            As[lk + 0][lr] = v.x; As[lk + 1][lr] = v.y;
            As[lk + 2][lr] = v.z; As[lk + 3][lr] = v.w;
        }
        {
            int n = n0 + lr;
            float4 v = make_float4(0.f, 0.f, 0.f, 0.f);
            if (n < N) v = *(const float4*)(B + (size_t)n * ldb + k0 + lk);
            Bs[lk + 0][lr] = v.x; Bs[lk + 1][lr] = v.y;
            Bs[lk + 2][lr] = v.z; Bs[lk + 3][lr] = v.w;
        }
        __syncthreads();
        #pragma unroll
        for (int kk = 0; kk < KT; ++kk) {
            float4 a4 = *(const float4*)&As[kk][ty * 4];
            float4 b4 = *(const float4*)&Bs[kk][tx * 4];
            float av[4] = {a4.x, a4.y, a4.z, a4.w};
            float bv[4] = {b4.x, b4.y, b4.z, b4.w};
            #pragma unroll
            for (int i = 0; i < 4; ++i)
                #pragma unroll
                for (int j = 0; j < 4; ++j)
                    acc[i][j] += av[i] * bv[j];
        }
        __syncthreads();
    }

    #pragma unroll
    for (int i = 0; i < 4; ++i) {
        int m = m0 + ty * 4 + i;
        #pragma unroll
        for (int j = 0; j < 4; ++j) {
            int n = n0 + tx * 4 + j;
            if (n < N) atomicAdd(&C[(size_t)m * ldc + n], acc[i][j]);
        }
    }
}

// ---------------------------------------------------------------------------
// bf16 MFMA NT GEMM — both operands pre-converted bf16 (uint4 passthrough
// staging). 128x128 tile, BK=64, 4 waves, mfma_f32_16x16x32_bf16, LDS_S=72.
// ---------------------------------------------------------------------------
using bf16x8 = __attribute__((ext_vector_type(8))) short;
using f32x4  = __attribute__((ext_vector_type(4))) float;

#define BBM 128
#define BBN 128
#define BBK 64
#define LDS_S (BBK + 8)   // 72 bf16 -> 144B row stride

__global__ __launch_bounds__(256)
void gemm_bf16_nt(const unsigned short* __restrict__ A, const unsigned short* __restrict__ Bw,
                  float* __restrict__ C, int M, int N, int K)
{
    __shared__ unsigned short As[BBM * LDS_S];
    __shared__ unsigned short Bs[BBN * LDS_S];

    int tid = threadIdx.x;
    int m0 = blockIdx.y * BBM, n0 = blockIdx.x * BBN;
    int lane = tid & 63, w = tid >> 6;
    int wm = (w >> 1) * 64, wn = (w & 1) * 64;
    int lm = lane & 15, q = lane >> 4;

    int lr = tid >> 3;          // 0..31  (staging row)
    int lc = (tid & 7) * 8;     // 0..56  (staging col, bf16 elems)

    f32x4 acc[4][4] = {};

    for (int k0 = 0; k0 < K; k0 += BBK) {
        #pragma unroll
        for (int r = 0; r < 4; ++r) {
            int row = lr + r * 32;
            uint4 av = *(const uint4*)(A + (size_t)(m0 + row) * K + k0 + lc);
            *(uint4*)&As[row * LDS_S + lc] = av;
        }
        #pragma unroll
        for (int r = 0; r < 4; ++r) {
            int row = lr + r * 32;
            uint4 pv = *(const uint4*)(Bw + (size_t)(n0 + row) * K + k0 + lc);
            *(uint4*)&Bs[row * LDS_S + lc] = pv;
        }
        __syncthreads();
        #pragma unroll
        for (int kk = 0; kk < BBK; kk += 32) {
            bf16x8 af[4], bf[4];
            #pragma unroll
            for (int i = 0; i < 4; ++i)
                af[i] = *(const bf16x8*)&As[(wm + i * 16 + lm) * LDS_S + kk + q * 8];
            #pragma unroll
            for (int j = 0; j < 4; ++j)
                bf[j] = *(const bf16x8*)&Bs[(wn + j * 16 + lm) * LDS_S + kk + q * 8];
            #pragma unroll
            for (int i = 0; i < 4; ++i)
                #pragma unroll
                for (int j = 0; j < 4; ++j)
                    acc[i][j] = __builtin_amdgcn_mfma_f32_16x16x32_bf16(
                        af[i], bf[j], acc[i][j], 0, 0, 0);
        }
        __syncthreads();
    }

    #pragma unroll
    for (int i = 0; i < 4; ++i)
        #pragma unroll
        for (int j = 0; j < 4; ++j)
            #pragma unroll
            for (int r = 0; r < 4; ++r) {
                int row = m0 + wm + i * 16 + q * 4 + r;
                int col = n0 + wn + j * 16 + lm;
                C[(size_t)row * N + col] = acc[i][j][r];
            }
}

// ---------------------------------------------------------------------------
// Depthwise causal conv (width 4) + bias + SiLU (r3-proven interleaved form).
// ---------------------------------------------------------------------------
__global__ __launch_bounds__(256)
void conv_silu_kernel(const float* __restrict__ xz, const float* __restrict__ cw,
                      const float* __restrict__ cb, float* __restrict__ xc)
{
    int idx = blockIdx.x * 256 + threadIdx.x;
    int d  = idx & (D_INNER - 1);
    int t  = (idx >> 11) & (LSEQ - 1);
    int bb = idx >> 21;

    const float* xcol = xz + (size_t)bb * LSEQ * 2 * D_INNER + d;
    float acc = cb[d];
    #pragma unroll
    for (int k = 0; k < D_CONV; ++k) {
        int tt = t + k - (D_CONV - 1);
        if (tt >= 0) acc += xcol[(size_t)tt * 2 * D_INNER] * cw[d * D_CONV + k];
    }
    acc = acc / (1.f + __expf(-acc));
    xc[idx] = acc;
}

// ---------------------------------------------------------------------------
// Chunked selective scan, v6: 2 lanes per d (8 states each) -> 4096 waves
// (4/SIMD, was 2); unroll-2 + prefetch-distance-2 software pipeline (named
// E/O register sets, static indexing). One shfl_xor(p,1,2) per step.
// Interleaved [r][d] operand layout (r3/r5-proven cache behavior).
// ---------------------------------------------------------------------------
#define UNPK4(dst, off, v) { dst[(off)+0]=(v).x; dst[(off)+1]=(v).y; \
                             dst[(off)+2]=(v).z; dst[(off)+3]=(v).w; }

__global__ __launch_bounds__(256)
void scan_pass1(const float* __restrict__ dtb, const float* __restrict__ xc,
                const float* __restrict__ dbl, const float* __restrict__ Alog,
                float* __restrict__ aPbuf, float* __restrict__ bAbuf)
{
    int tid  = threadIdx.x;
    int half = tid & 1;              // states half*8 .. half*8+7
    int blk  = blockIdx.x;           // grid = NB * NCHUNK * 16 = 1024
    int dg   = blk & 15;
    int c    = (blk >> 4) & (NCHUNK - 1);
    int bb   = blk >> 9;
    int d    = dg * 128 + (tid >> 1);

    float A[8];
    {
        const float* pA = Alog + (size_t)d * D_STATE + half * 8;
        float4 v0 = *(const float4*)pA;
        float4 v1 = *(const float4*)(pA + 4);
        A[0] = -__expf(v0.x); A[1] = -__expf(v0.y);
        A[2] = -__expf(v0.z); A[3] = -__expf(v0.w);
        A[4] = -__expf(v1.x); A[5] = -__expf(v1.y);
        A[6] = -__expf(v1.z); A[7] = -__expf(v1.w);
    }

    size_t rowbase = (size_t)bb * LSEQ + (size_t)c * TCH;
    const float* pdt = dtb + rowbase * D_INNER + d;
    const float* pxc = xc  + rowbase * D_INNER + d;
    const float* pbc = dbl + rowbase * 96 + DT_RANK + half * 8;

    float aP[8] = {1.f,1.f,1.f,1.f,1.f,1.f,1.f,1.f};
    float bA[8] = {0.f,0.f,0.f,0.f,0.f,0.f,0.f,0.f};

    // prefetch steps 0 (E) and 1 (O)
    float  dtE = pdt[0], xvE = pxc[0];
    float4 BE0 = *(const float4*)pbc;
    float4 BE1 = *(const float4*)(pbc + 4);
    float  dtO = pdt[D_INNER], xvO = pxc[D_INNER];
    float4 BO0 = *(const float4*)(pbc + 96);
    float4 BO1 = *(const float4*)(pbc + 96 + 4);

    for (int t = 0; t < TCH; t += 2) {
        int t2 = (t + 2 < TCH) ? t + 2 : TCH - 1;
        int t3 = (t + 3 < TCH) ? t + 3 : TCH - 1;
        float  dtEn = pdt[(size_t)t2 * D_INNER], xvEn = pxc[(size_t)t2 * D_INNER];
        float4 BE0n = *(const float4*)(pbc + (size_t)t2 * 96);
        float4 BE1n = *(const float4*)(pbc + (size_t)t2 * 96 + 4);
        float  dtOn = pdt[(size_t)t3 * D_INNER], xvOn = pxc[(size_t)t3 * D_INNER];
        float4 BO0n = *(const float4*)(pbc + (size_t)t3 * 96);
        float4 BO1n = *(const float4*)(pbc + (size_t)t3 * 96 + 4);

        {   // step t
            float B[8];
            UNPK4(B, 0, BE0) UNPK4(B, 4, BE1)
            float dtx = dtE * xvE;
            #pragma unroll
            for (int s = 0; s < 8; ++s) {
                float a = __expf(dtE * A[s]);
                aP[s] *= a;
                bA[s] = bA[s] * a + dtx * B[s];
            }
        }
        {   // step t+1
            float B[8];
            UNPK4(B, 0, BO0) UNPK4(B, 4, BO1)
            float dtx = dtO * xvO;
            #pragma unroll
            for (int s = 0; s < 8; ++s) {
                float a = __expf(dtO * A[s]);
                aP[s] *= a;
                bA[s] = bA[s] * a + dtx * B[s];
            }
        }
        dtE = dtEn; xvE = xvEn; BE0 = BE0n; BE1 = BE1n;
        dtO = dtOn; xvO = xvOn; BO0 = BO0n; BO1 = BO1n;
    }

    float* pa = aPbuf + ((size_t)(bb * NCHUNK + c) * D_INNER + d) * D_STATE + half * 8;
    float* pb = bAbuf + ((size_t)(bb * NCHUNK + c) * D_INNER + d) * D_STATE + half * 8;
    *(float4*)(pa + 0) = make_float4(aP[0], aP[1], aP[2], aP[3]);
    *(float4*)(pa + 4) = make_float4(aP[4], aP[5], aP[6], aP[7]);
    *(float4*)(pb + 0) = make_float4(bA[0], bA[1], bA[2], bA[3]);
    *(float4*)(pb + 4) = make_float4(bA[4], bA[5], bA[6], bA[7]);
}

__global__ __launch_bounds__(256)
void scan_pass2(const float* __restrict__ dtb, const float* __restrict__ xc,
                const float* __restrict__ dbl, const float* __restrict__ xz,
                const float* __restrict__ Alog, const float* __restrict__ Dp,
                const float* __restrict__ aPbuf, const float* __restrict__ bAbuf,
                unsigned short* __restrict__ y)
{
    int tid  = threadIdx.x;
    int half = tid & 1;
    int blk  = blockIdx.x;
    int dg   = blk & 15;
    int c    = (blk >> 4) & (NCHUNK - 1);
    int bb   = blk >> 9;
    int d    = dg * 128 + (tid >> 1);

    float A[8];
    {
        const float* pA = Alog + (size_t)d * D_STATE + half * 8;
        float4 v0 = *(const float4*)pA;
        float4 v1 = *(const float4*)(pA + 4);
        A[0] = -__expf(v0.x); A[1] = -__expf(v0.y);
        A[2] = -__expf(v0.z); A[3] = -__expf(v0.w);
        A[4] = -__expf(v1.x); A[5] = -__expf(v1.y);
        A[6] = -__expf(v1.z); A[7] = -__expf(v1.w);
    }
    float Dd = Dp[d];

    float h[8] = {0.f,0.f,0.f,0.f,0.f,0.f,0.f,0.f};

    // prefix compose over chunks [0, c)
    for (int cc = 0; cc < c; ++cc) {
        const float* pa = aPbuf + ((size_t)(bb * NCHUNK + cc) * D_INNER + d) * D_STATE + half * 8;
        const float* pb = bAbuf + ((size_t)(bb * NCHUNK + cc) * D_INNER + d) * D_STATE + half * 8;
        float4 a0 = *(const float4*)(pa + 0), a1 = *(const float4*)(pa + 4);
        float4 b0 = *(const float4*)(pb + 0), b1 = *(const float4*)(pb + 4);
        float av[8], bv[8];
        UNPK4(av, 0, a0) UNPK4(av, 4, a1)
        UNPK4(bv, 0, b0) UNPK4(bv, 4, b1)
        #pragma unroll
        for (int s = 0; s < 8; ++s) h[s] = h[s] * av[s] + bv[s];
    }

    size_t rowbase = (size_t)bb * LSEQ + (size_t)c * TCH;
    const float* pdt = dtb + rowbase * D_INNER + d;
    const float* pxc = xc  + rowbase * D_INNER + d;
    const float* pz  = xz  + rowbase * 2 * D_INNER + D_INNER + d;
    const float* pbc = dbl + rowbase * 96 + DT_RANK + half * 8;
    unsigned short* py = y + rowbase * D_INNER + d;

    // prefetch steps 0 (E) and 1 (O)
    float  dtE = pdt[0], xvE = pxc[0], zvE = pz[0];
    float4 BE0 = *(const float4*)pbc;
    float4 BE1 = *(const float4*)(pbc + 4);
    float4 CE0 = *(const float4*)(pbc + 16);
    float4 CE1 = *(const float4*)(pbc + 20);
    float  dtO = pdt[D_INNER], xvO = pxc[D_INNER], zvO = pz[2 * D_INNER];
    float4 BO0 = *(const float4*)(pbc + 96);
    float4 BO1 = *(const float4*)(pbc + 96 + 4);
    float4 CO0 = *(const float4*)(pbc + 96 + 16);
    float4 CO1 = *(const float4*)(pbc + 96 + 20);

    for (int t = 0; t < TCH; t += 2) {
        int t2 = (t + 2 < TCH) ? t + 2 : TCH - 1;
        int t3 = (t + 3 < TCH) ? t + 3 : TCH - 1;
        float  dtEn = pdt[(size_t)t2 * D_INNER], xvEn = pxc[(size_t)t2 * D_INNER];
        float  zvEn = pz[(size_t)t2 * 2 * D_INNER];
        float4 BE0n = *(const float4*)(pbc + (size_t)t2 * 96);
        float4 BE1n = *(const float4*)(pbc + (size_t)t2 * 96 + 4);
        float4 CE0n = *(const float4*)(pbc + (size_t)t2 * 96 + 16);
        float4 CE1n = *(const float4*)(pbc + (size_t)t2 * 96 + 20);
        float  dtOn = pdt[(size_t)t3 * D_INNER], xvOn = pxc[(size_t)t3 * D_INNER];
        float  zvOn = pz[(size_t)t3 * 2 * D_INNER];
        float4 BO0n = *(const float4*)(pbc + (size_t)t3 * 96);
        float4 BO1n = *(const float4*)(pbc + (size_t)t3 * 96 + 4);
        float4 CO0n = *(const float4*)(pbc + (size_t)t3 * 96 + 16);
        float4 CO1n = *(const float4*)(pbc + (size_t)t3 * 96 + 20);

        {   // step t
            float B[8], C[8];
            UNPK4(B, 0, BE0) UNPK4(B, 4, BE1)
            UNPK4(C, 0, CE0) UNPK4(C, 4, CE1)
            float dtx = dtE * xvE;
            float p = 0.f;
            #pragma unroll
            for (int s = 0; s < 8; ++s) {
                float a = __expf(dtE * A[s]);
                h[s] = h[s] * a + dtx * B[s];
                p += h[s] * C[s];
            }
            p += __shfl_xor(p, 1, 2);
            if (half == 0) {
                float sz = zvE / (1.f + __expf(-zvE));
                py[(size_t)t * D_INNER] = (unsigned short)bfbits((p + xvE * Dd) * sz);
            }
        }
        {   // step t+1
            float B[8], C[8];
            UNPK4(B, 0, BO0) UNPK4(B, 4, BO1)
            UNPK4(C, 0, CO0) UNPK4(C, 4, CO1)
            float dtx = dtO * xvO;
            float p = 0.f;
            #pragma unroll
            for (int s = 0; s < 8; ++s) {
                float a = __expf(dtO * A[s]);
                h[s] = h[s] * a + dtx * B[s];
                p += h[s] * C[s];
            }
            p += __shfl_xor(p, 1, 2);
            if (half == 0) {
                float sz = zvO / (1.f + __expf(-zvO));
                py[(size_t)(t + 1) * D_INNER] = (unsigned short)bfbits((p + xvO * Dd) * sz);
            }
        }
        dtE = dtEn; xvE = xvEn; zvE = zvEn;
        BE0 = BE0n; BE1 = BE1n; CE0 = CE0n; CE1 = CE1n;
        dtO = dtOn; xvO = xvOn; zvO = zvOn;
        BO0 = BO0n; BO1 = BO1n; CO0 = CO0n; CO1 = CO1n;
    }
}

// ---------------------------------------------------------------------------
extern "C" void kernel_launch(void* const* d_in, const int* in_sizes, int n_in,
                              void* d_out, int out_size, void* d_ws, size_t ws_size,
                              hipStream_t stream)
{
    const float* h_in  = (const float*)d_in[0];
    const float* iw    = (const float*)d_in[1];   // (4, 4096, 1024)
    const float* cw    = (const float*)d_in[2];   // (4, 2048, 4)
    const float* cb    = (const float*)d_in[3];   // (4, 2048)
    const float* xw    = (const float*)d_in[4];   // (4, 96, 2048)
    const float* dw    = (const float*)d_in[5];   // (4, 2048, 64)
    const float* db    = (const float*)d_in[6];   // (4, 2048)
    const float* Alog  = (const float*)d_in[7];   // (4, 2048, 16)
    const float* Dp    = (const float*)d_in[8];   // (4, 2048)
    const float* ow    = (const float*)d_in[9];   // (4, 1024, 2048)
    const float* nw    = (const float*)d_in[10];  // (4, 1024)
    const float* nb    = (const float*)d_in[11];  // (4, 1024)
    const float* nfw   = (const float*)d_in[12];  // (1024,)
    const float* nfb   = (const float*)d_in[13];  // (1024,)

    // workspace layout — identical total (25,362,432 floats)
    float* ws = (float*)d_ws;
    float* residual = ws;                       // 2,097,152
    float* hs       = residual + 2097152;       // 2,097,152 (aPbuf + out_proj out)
    float* xz       = hs + 2097152;             // 8,388,608  [r][4096]
    float* xc       = xz + 8388608;             // 4,194,304  [r][2048]
    float* dtb      = xc + 4194304;             // 4,194,304  [r][2048]
    float* dbl      = dtb + 4194304;            // 196,608    [r][96]
    float* y        = dbl + 196608;             // 4,194,304

    // aPbuf (2M floats) aliases hs (dead between in_proj-consume and out_proj).
    // bAbuf (2M floats) lives in y[2M..4M).
    float* aPbuf = hs;
    float* bAbuf = y + 2097152;

    // bf16 staging in dead regions:
    //  - wbuf_in  (in_proj w bf16, 2M floats)  -> y[0 .. 2M)
    //  - hs_bf16  (LN out bf16,   1M floats)   -> y[2M .. 3M) (dead before scan)
    //  - y_bf16   (scan out bf16, 2M floats)   -> y[0 .. 2M)
    //  - wbuf_out (out_proj w bf16, 1M floats) -> dtb[0 .. 1M) (dead after scan)
    unsigned short* wbuf_in  = (unsigned short*)y;
    unsigned short* hs_bf16  = (unsigned short*)(y + 2097152);
    unsigned short* y_bf16   = (unsigned short*)y;
    unsigned short* wbuf_out = (unsigned short*)dtb;

    const float* cur_add = h_in;
    for (int i = 0; i < N_LAYER; ++i) {
        // residual add + LN, emit bf16
        add_ln_kernel<<<NROWS, 256, 0, stream>>>(cur_add, residual,
                                                 nw + i * D_MODEL, nb + i * D_MODEL,
                                                 hs_bf16, i == 0, 1);
        // convert in_proj weights -> bf16 (dead y space)
        f32_to_bf16_kernel<<<(2 * D_INNER * D_MODEL) / 1024, 256, 0, stream>>>(
            iw + (size_t)i * 2 * D_INNER * D_MODEL, wbuf_in);
        // in_proj (bf16 MFMA): -> xz [r][4096] fp32
        gemm_bf16_nt<<<dim3(2 * D_INNER / BBN, NROWS / BBM), 256, 0, stream>>>(
            hs_bf16, wbuf_in, xz, NROWS, 2 * D_INNER, D_MODEL);
        // conv + silu -> xc [r][2048]
        conv_silu_kernel<<<NB * LSEQ * D_INNER / 256, 256, 0, stream>>>(
            xz, cw + (size_t)i * D_INNER * D_CONV, cb + i * D_INNER, xc);
        // x_proj (fp32 split-K x8): -> dbl [r][96]
        hipMemsetAsync(dbl, 0, 196608 * sizeof(float), stream);
        gemm_nt_splitk<<<dim3(2, NROWS / TILE, 8), 256, 0, stream>>>(
            xc, xw + (size_t)i * 96 * D_INNER, dbl,
            NROWS, 96, D_INNER, D_INNER, D_INNER, 96, D_INNER / 8);
        // dt_proj + softplus: -> dtb [r][2048]
        gemm_nt<<<dim3(D_INNER / TILE, NROWS / TILE), 256, 0, stream>>>(
            dbl, dw + (size_t)i * D_INNER * DT_RANK, dtb,
            NROWS, D_INNER, DT_RANK, 96, DT_RANK, D_INNER, db + i * D_INNER, 1);
        // chunked selective scan — 2 lanes/d, 4096 waves, depth-2 pipeline
        scan_pass1<<<NB * NCHUNK * (D_INNER / 128), 256, 0, stream>>>(
            dtb, xc, dbl, Alog + (size_t)i * D_INNER * D_STATE, aPbuf, bAbuf);
        scan_pass2<<<NB * NCHUNK * (D_INNER / 128), 256, 0, stream>>>(
            dtb, xc, dbl, xz, Alog + (size_t)i * D_INNER * D_STATE, Dp + i * D_INNER,
            aPbuf, bAbuf, y_bf16);
        // convert out_proj weights -> bf16 (dead dtb space)
        f32_to_bf16_kernel<<<(D_MODEL * D_INNER) / 1024, 256, 0, stream>>>(
            ow + (size_t)i * D_MODEL * D_INNER, wbuf_out);
        // out_proj (bf16 MFMA): -> hs [r][1024] fp32
        gemm_bf16_nt<<<dim3(D_MODEL / BBN, NROWS / BBM), 256, 0, stream>>>(
            y_bf16, wbuf_out, hs, NROWS, D_MODEL, D_INNER);
        cur_add = hs;
    }
    add_ln_kernel<<<NROWS, 256, 0, stream>>>(hs, residual, nfw, nfb, d_out, 0, 0);
}

// Round 7
// 1006.043 us; speedup vs baseline: 1.2866x; 1.0433x over previous
//
#include <hip/hip_runtime.h>
#include <math.h>

#define D_MODEL 1024
#define D_INNER 2048
#define D_STATE 16
#define D_CONV  4
#define DT_RANK 64
#define NB      2
#define LSEQ    1024
#define NROWS   (NB * LSEQ)   // 2048
#define LN_EPS  1e-5f
#define N_LAYER 4
#define NCHUNK  32
#define TCH     (LSEQ / NCHUNK)   // 32 steps per chunk

__device__ inline unsigned bfbits(float f) {
    unsigned u = __float_as_uint(f);
    return (u + 0x7fffu + ((u >> 16) & 1u)) >> 16;  // RNE
}

// ---------------------------------------------------------------------------
// Fused residual-add + LayerNorm. bf16out=1: emit bf16; 0: fp32.
// ---------------------------------------------------------------------------
__device__ inline float wave_sum(float s) {
    #pragma unroll
    for (int m = 1; m < 64; m <<= 1) s += __shfl_xor(s, m, 64);
    return s;
}

__global__ __launch_bounds__(256)
void add_ln_kernel(const float* __restrict__ add, float* __restrict__ residual,
                   const float* __restrict__ w, const float* __restrict__ b,
                   void* __restrict__ out, int first, int bf16out)
{
    int row = blockIdx.x;
    int tid = threadIdx.x;
    size_t base = (size_t)row * D_MODEL + tid * 4;

    float4 v = *(const float4*)(add + base);
    if (!first) {
        float4 r = *(const float4*)(residual + base);
        v.x += r.x; v.y += r.y; v.z += r.z; v.w += r.w;
    }
    *(float4*)(residual + base) = v;

    __shared__ float red[8];
    float s = v.x + v.y + v.z + v.w;
    s = wave_sum(s);
    if ((tid & 63) == 0) red[tid >> 6] = s;
    __syncthreads();
    float mu = (red[0] + red[1] + red[2] + red[3]) * (1.0f / D_MODEL);

    float dx = v.x - mu, dy = v.y - mu, dz = v.z - mu, dw2 = v.w - mu;
    float s2 = dx*dx + dy*dy + dz*dz + dw2*dw2;
    s2 = wave_sum(s2);
    if ((tid & 63) == 0) red[4 + (tid >> 6)] = s2;
    __syncthreads();
    float var = (red[4] + red[5] + red[6] + red[7]) * (1.0f / D_MODEL);
    float rs = rsqrtf(var + LN_EPS);

    float4 wv = *(const float4*)(w + tid * 4);
    float4 bv = *(const float4*)(b + tid * 4);
    float4 o;
    o.x = dx  * rs * wv.x + bv.x;
    o.y = dy  * rs * wv.y + bv.y;
    o.z = dz  * rs * wv.z + bv.z;
    o.w = dw2 * rs * wv.w + bv.w;
    if (bf16out) {
        ushort4 ov;
        ov.x = (unsigned short)bfbits(o.x);
        ov.y = (unsigned short)bfbits(o.y);
        ov.z = (unsigned short)bfbits(o.z);
        ov.w = (unsigned short)bfbits(o.w);
        *(ushort4*)((unsigned short*)out + base) = ov;
    } else {
        *(float4*)((float*)out + base) = o;
    }
}

// ---------------------------------------------------------------------------
// fp32 -> bf16 bulk convert (weights). grid*256*4 must equal element count.
// ---------------------------------------------------------------------------
__global__ __launch_bounds__(256)
void f32_to_bf16_kernel(const float* __restrict__ src, unsigned short* __restrict__ dst)
{
    int i = blockIdx.x * 256 + threadIdx.x;
    float4 v = *(const float4*)(src + (size_t)i * 4);
    ushort4 o;
    o.x = (unsigned short)bfbits(v.x);
    o.y = (unsigned short)bfbits(v.y);
    o.z = (unsigned short)bfbits(v.z);
    o.w = (unsigned short)bfbits(v.w);
    *(ushort4*)(dst + (size_t)i * 4) = o;
}

// ---------------------------------------------------------------------------
// fp32 -> hi/lo bf16 split convert (a = hi + lo, each bf16; ~fp32 accuracy
// when used as ah*bh + ah*bl + al*bh). grid*1024 elements.
// ---------------------------------------------------------------------------
__global__ __launch_bounds__(256)
void f32_to_hl_kernel(const float* __restrict__ src, unsigned short* __restrict__ hi,
                      unsigned short* __restrict__ lo)
{
    int i = blockIdx.x * 256 + threadIdx.x;
    float4 v = *(const float4*)(src + (size_t)i * 4);
    ushort4 h, l;
    float f;
    h.x = (unsigned short)bfbits(v.x); f = __uint_as_float((unsigned)h.x << 16); l.x = (unsigned short)bfbits(v.x - f);
    h.y = (unsigned short)bfbits(v.y); f = __uint_as_float((unsigned)h.y << 16); l.y = (unsigned short)bfbits(v.y - f);
    h.z = (unsigned short)bfbits(v.z); f = __uint_as_float((unsigned)h.z << 16); l.z = (unsigned short)bfbits(v.z - f);
    h.w = (unsigned short)bfbits(v.w); f = __uint_as_float((unsigned)h.w << 16); l.w = (unsigned short)bfbits(v.w - f);
    *(ushort4*)(hi + (size_t)i * 4) = h;
    *(ushort4*)(lo + (size_t)i * 4) = l;
}

// ---------------------------------------------------------------------------
// Extract dt-low columns (0..63) of dbl [2048][96] -> compact hi/lo bf16
// [2048][64]. 32768 threads (128 blocks), float4 per thread.
// ---------------------------------------------------------------------------
__global__ __launch_bounds__(256)
void dtlow_hl_kernel(const float* __restrict__ dbl, unsigned short* __restrict__ hi,
                     unsigned short* __restrict__ lo)
{
    int idx = blockIdx.x * 256 + threadIdx.x;   // 2048*16
    int m = idx >> 4, k4 = (idx & 15) * 4;
    float4 v = *(const float4*)(dbl + (size_t)m * 96 + k4);
    ushort4 h, l;
    float f;
    h.x = (unsigned short)bfbits(v.x); f = __uint_as_float((unsigned)h.x << 16); l.x = (unsigned short)bfbits(v.x - f);
    h.y = (unsigned short)bfbits(v.y); f = __uint_as_float((unsigned)h.y << 16); l.y = (unsigned short)bfbits(v.y - f);
    h.z = (unsigned short)bfbits(v.z); f = __uint_as_float((unsigned)h.z << 16); l.z = (unsigned short)bfbits(v.z - f);
    h.w = (unsigned short)bfbits(v.w); f = __uint_as_float((unsigned)h.w << 16); l.w = (unsigned short)bfbits(v.w - f);
    *(ushort4*)(hi + (size_t)m * 64 + k4) = h;
    *(ushort4*)(lo + (size_t)m * 64 + k4) = l;
}

// ---------------------------------------------------------------------------
// bf16 MFMA NT GEMM — both operands pre-converted bf16 (uint4 passthrough
// staging). 128x128 tile, BK=64, 4 waves, mfma_f32_16x16x32_bf16, LDS_S=72.
// ---------------------------------------------------------------------------
using bf16x8 = __attribute__((ext_vector_type(8))) short;
using f32x4  = __attribute__((ext_vector_type(4))) float;

#define BBM 128
#define BBN 128
#define BBK 64
#define LDS_S (BBK + 8)   // 72 bf16 -> 144B row stride

__global__ __launch_bounds__(256)
void gemm_bf16_nt(const unsigned short* __restrict__ A, const unsigned short* __restrict__ Bw,
                  float* __restrict__ C, int M, int N, int K)
{
    __shared__ unsigned short As[BBM * LDS_S];
    __shared__ unsigned short Bs[BBN * LDS_S];

    int tid = threadIdx.x;
    int m0 = blockIdx.y * BBM, n0 = blockIdx.x * BBN;
    int lane = tid & 63, w = tid >> 6;
    int wm = (w >> 1) * 64, wn = (w & 1) * 64;
    int lm = lane & 15, q = lane >> 4;

    int lr = tid >> 3;          // 0..31  (staging row)
    int lc = (tid & 7) * 8;     // 0..56  (staging col, bf16 elems)

    f32x4 acc[4][4] = {};

    for (int k0 = 0; k0 < K; k0 += BBK) {
        #pragma unroll
        for (int r = 0; r < 4; ++r) {
            int row = lr + r * 32;
            uint4 av = *(const uint4*)(A + (size_t)(m0 + row) * K + k0 + lc);
            *(uint4*)&As[row * LDS_S + lc] = av;
        }
        #pragma unroll
        for (int r = 0; r < 4; ++r) {
            int row = lr + r * 32;
            uint4 pv = *(const uint4*)(Bw + (size_t)(n0 + row) * K + k0 + lc);
            *(uint4*)&Bs[row * LDS_S + lc] = pv;
        }
        __syncthreads();
        #pragma unroll
        for (int kk = 0; kk < BBK; kk += 32) {
            bf16x8 af[4], bf[4];
            #pragma unroll
            for (int i = 0; i < 4; ++i)
                af[i] = *(const bf16x8*)&As[(wm + i * 16 + lm) * LDS_S + kk + q * 8];
            #pragma unroll
            for (int j = 0; j < 4; ++j)
                bf[j] = *(const bf16x8*)&Bs[(wn + j * 16 + lm) * LDS_S + kk + q * 8];
            #pragma unroll
            for (int i = 0; i < 4; ++i)
                #pragma unroll
                for (int j = 0; j < 4; ++j)
                    acc[i][j] = __builtin_amdgcn_mfma_f32_16x16x32_bf16(
                        af[i], bf[j], acc[i][j], 0, 0, 0);
        }
        __syncthreads();
    }

    #pragma unroll
    for (int i = 0; i < 4; ++i)
        #pragma unroll
        for (int j = 0; j < 4; ++j)
            #pragma unroll
            for (int r = 0; r < 4; ++r) {
                int row = m0 + wm + i * 16 + q * 4 + r;
                int col = n0 + wn + j * 16 + lm;
                C[(size_t)row * N + col] = acc[i][j][r];
            }
}

// ---------------------------------------------------------------------------
// x_proj via hi/lo split-bf16 MFMA, split-K, NO LDS (direct global fragment
// loads: lanes lm=rows, q=k-slices -> full 64B line utilization).
// A: xc_hi/lo [2048][2048]; B: xwp_hi/lo [96][2048]; C: dbl [2048][96] atomic.
// Grid: dim3(64 mtile(32 rows), 8 z(kslice 256)). 4 waves: 2 m-halves x 2 n-halves.
// ---------------------------------------------------------------------------
__global__ __launch_bounds__(256)
void xproj_hl(const unsigned short* __restrict__ Ah, const unsigned short* __restrict__ Al,
              const unsigned short* __restrict__ Bh, const unsigned short* __restrict__ Bl,
              float* __restrict__ C)
{
    int tid = threadIdx.x;
    int lane = tid & 63, w = tid >> 6;
    int lm = lane & 15, q = lane >> 4;
    int m0 = blockIdx.x * 32;
    int kb = blockIdx.y * 256;

    int wm = (w & 1) * 16;          // m-half
    int wn = (w >> 1) * 48;         // n-half (3 frags of 16)

    size_t arow = (size_t)(m0 + wm + lm) * 2048;

    f32x4 acc[3] = {};

    #pragma unroll 2
    for (int kc = 0; kc < 8; ++kc) {
        int k = kb + kc * 32 + q * 8;
        bf16x8 ah = *(const bf16x8*)&Ah[arow + k];
        bf16x8 al = *(const bf16x8*)&Al[arow + k];
        #pragma unroll
        for (int j = 0; j < 3; ++j) {
            size_t brow = (size_t)(wn + j * 16 + lm) * 2048;
            bf16x8 bh = *(const bf16x8*)&Bh[brow + k];
            bf16x8 bl = *(const bf16x8*)&Bl[brow + k];
            acc[j] = __builtin_amdgcn_mfma_f32_16x16x32_bf16(al, bh, acc[j], 0, 0, 0);
            acc[j] = __builtin_amdgcn_mfma_f32_16x16x32_bf16(ah, bl, acc[j], 0, 0, 0);
            acc[j] = __builtin_amdgcn_mfma_f32_16x16x32_bf16(ah, bh, acc[j], 0, 0, 0);
        }
    }

    #pragma unroll
    for (int j = 0; j < 3; ++j) {
        int col = wn + j * 16 + lm;
        #pragma unroll
        for (int r = 0; r < 4; ++r) {
            int row = m0 + wm + q * 4 + r;
            atomicAdd(&C[(size_t)row * 96 + col], acc[j][r]);
        }
    }
}

// ---------------------------------------------------------------------------
// dt_proj via hi/lo split-bf16 MFMA + fused bias+softplus. NO LDS.
// A: dtlow_hi/lo [2048][64]; B: dw_hi/lo [2048][64]; out dtb [2048][2048] fp32.
// Grid: dim3(16 ntile(128), 32 mtile(64)). 4 waves: 16 m-rows each, 8 n-frags.
// ---------------------------------------------------------------------------
__global__ __launch_bounds__(256)
void dtproj_hl(const unsigned short* __restrict__ Ah, const unsigned short* __restrict__ Al,
               const unsigned short* __restrict__ Bh, const unsigned short* __restrict__ Bl,
               const float* __restrict__ bias, float* __restrict__ dtb)
{
    int tid = threadIdx.x;
    int lane = tid & 63, w = tid >> 6;
    int lm = lane & 15, q = lane >> 4;
    int n0 = blockIdx.x * 128;
    int m0 = blockIdx.y * 64;

    size_t arow = (size_t)(m0 + w * 16 + lm) * 64;

    f32x4 acc[8] = {};

    #pragma unroll
    for (int kc = 0; kc < 2; ++kc) {
        int k = kc * 32 + q * 8;
        bf16x8 ah = *(const bf16x8*)&Ah[arow + k];
        bf16x8 al = *(const bf16x8*)&Al[arow + k];
        #pragma unroll
        for (int j = 0; j < 8; ++j) {
            size_t brow = (size_t)(n0 + j * 16 + lm) * 64;
            bf16x8 bh = *(const bf16x8*)&Bh[brow + k];
            bf16x8 bl = *(const bf16x8*)&Bl[brow + k];
            acc[j] = __builtin_amdgcn_mfma_f32_16x16x32_bf16(al, bh, acc[j], 0, 0, 0);
            acc[j] = __builtin_amdgcn_mfma_f32_16x16x32_bf16(ah, bl, acc[j], 0, 0, 0);
            acc[j] = __builtin_amdgcn_mfma_f32_16x16x32_bf16(ah, bh, acc[j], 0, 0, 0);
        }
    }

    #pragma unroll
    for (int j = 0; j < 8; ++j) {
        int col = n0 + j * 16 + lm;
        float bv = bias[col];
        #pragma unroll
        for (int r = 0; r < 4; ++r) {
            int row = m0 + w * 16 + q * 4 + r;
            float v = acc[j][r] + bv;
            v = (v > 20.f) ? v : log1pf(__expf(v));
            dtb[(size_t)row * D_INNER + col] = v;
        }
    }
}

// ---------------------------------------------------------------------------
// Depthwise causal conv (width 4) + bias + SiLU; also emits hi/lo bf16 split
// of the output for the MFMA x_proj.
// ---------------------------------------------------------------------------
__global__ __launch_bounds__(256)
void conv_silu_kernel(const float* __restrict__ xz, const float* __restrict__ cw,
                      const float* __restrict__ cb, float* __restrict__ xc,
                      unsigned short* __restrict__ xch, unsigned short* __restrict__ xcl)
{
    int idx = blockIdx.x * 256 + threadIdx.x;
    int d  = idx & (D_INNER - 1);
    int t  = (idx >> 11) & (LSEQ - 1);
    int bb = idx >> 21;

    const float* xcol = xz + (size_t)bb * LSEQ * 2 * D_INNER + d;
    float acc = cb[d];
    #pragma unroll
    for (int k = 0; k < D_CONV; ++k) {
        int tt = t + k - (D_CONV - 1);
        if (tt >= 0) acc += xcol[(size_t)tt * 2 * D_INNER] * cw[d * D_CONV + k];
    }
    acc = acc / (1.f + __expf(-acc));
    xc[idx] = acc;
    unsigned hb = bfbits(acc);
    xch[idx] = (unsigned short)hb;
    float hf = __uint_as_float(hb << 16);
    xcl[idx] = (unsigned short)bfbits(acc - hf);
}

// ---------------------------------------------------------------------------
// Chunked selective scan (r6-proven): 2 lanes per d (8 states each), 4096
// waves, unroll-2 + prefetch-distance-2 pipeline. Interleaved [r][d] layout.
// ---------------------------------------------------------------------------
#define UNPK4(dst, off, v) { dst[(off)+0]=(v).x; dst[(off)+1]=(v).y; \
                             dst[(off)+2]=(v).z; dst[(off)+3]=(v).w; }

__global__ __launch_bounds__(256)
void scan_pass1(const float* __restrict__ dtb, const float* __restrict__ xc,
                const float* __restrict__ dbl, const float* __restrict__ Alog,
                float* __restrict__ aPbuf, float* __restrict__ bAbuf)
{
    int tid  = threadIdx.x;
    int half = tid & 1;              // states half*8 .. half*8+7
    int blk  = blockIdx.x;           // grid = NB * NCHUNK * 16 = 1024
    int dg   = blk & 15;
    int c    = (blk >> 4) & (NCHUNK - 1);
    int bb   = blk >> 9;
    int d    = dg * 128 + (tid >> 1);

    float A[8];
    {
        const float* pA = Alog + (size_t)d * D_STATE + half * 8;
        float4 v0 = *(const float4*)pA;
        float4 v1 = *(const float4*)(pA + 4);
        A[0] = -__expf(v0.x); A[1] = -__expf(v0.y);
        A[2] = -__expf(v0.z); A[3] = -__expf(v0.w);
        A[4] = -__expf(v1.x); A[5] = -__expf(v1.y);
        A[6] = -__expf(v1.z); A[7] = -__expf(v1.w);
    }

    size_t rowbase = (size_t)bb * LSEQ + (size_t)c * TCH;
    const float* pdt = dtb + rowbase * D_INNER + d;
    const float* pxc = xc  + rowbase * D_INNER + d;
    const float* pbc = dbl + rowbase * 96 + DT_RANK + half * 8;

    float aP[8] = {1.f,1.f,1.f,1.f,1.f,1.f,1.f,1.f};
    float bA[8] = {0.f,0.f,0.f,0.f,0.f,0.f,0.f,0.f};

    // prefetch steps 0 (E) and 1 (O)
    float  dtE = pdt[0], xvE = pxc[0];
    float4 BE0 = *(const float4*)pbc;
    float4 BE1 = *(const float4*)(pbc + 4);
    float  dtO = pdt[D_INNER], xvO = pxc[D_INNER];
    float4 BO0 = *(const float4*)(pbc + 96);
    float4 BO1 = *(const float4*)(pbc + 96 + 4);

    for (int t = 0; t < TCH; t += 2) {
        int t2 = (t + 2 < TCH) ? t + 2 : TCH - 1;
        int t3 = (t + 3 < TCH) ? t + 3 : TCH - 1;
        float  dtEn = pdt[(size_t)t2 * D_INNER], xvEn = pxc[(size_t)t2 * D_INNER];
        float4 BE0n = *(const float4*)(pbc + (size_t)t2 * 96);
        float4 BE1n = *(const float4*)(pbc + (size_t)t2 * 96 + 4);
        float  dtOn = pdt[(size_t)t3 * D_INNER], xvOn = pxc[(size_t)t3 * D_INNER];
        float4 BO0n = *(const float4*)(pbc + (size_t)t3 * 96);
        float4 BO1n = *(const float4*)(pbc + (size_t)t3 * 96 + 4);

        {   // step t
            float B[8];
            UNPK4(B, 0, BE0) UNPK4(B, 4, BE1)
            float dtx = dtE * xvE;
            #pragma unroll
            for (int s = 0; s < 8; ++s) {
                float a = __expf(dtE * A[s]);
                aP[s] *= a;
                bA[s] = bA[s] * a + dtx * B[s];
            }
        }
        {   // step t+1
            float B[8];
            UNPK4(B, 0, BO0) UNPK4(B, 4, BO1)
            float dtx = dtO * xvO;
            #pragma unroll
            for (int s = 0; s < 8; ++s) {
                float a = __expf(dtO * A[s]);
                aP[s] *= a;
                bA[s] = bA[s] * a + dtx * B[s];
            }
        }
        dtE = dtEn; xvE = xvEn; BE0 = BE0n; BE1 = BE1n;
        dtO = dtOn; xvO = xvOn; BO0 = BO0n; BO1 = BO1n;
    }

    float* pa = aPbuf + ((size_t)(bb * NCHUNK + c) * D_INNER + d) * D_STATE + half * 8;
    float* pb = bAbuf + ((size_t)(bb * NCHUNK + c) * D_INNER + d) * D_STATE + half * 8;
    *(float4*)(pa + 0) = make_float4(aP[0], aP[1], aP[2], aP[3]);
    *(float4*)(pa + 4) = make_float4(aP[4], aP[5], aP[6], aP[7]);
    *(float4*)(pb + 0) = make_float4(bA[0], bA[1], bA[2], bA[3]);
    *(float4*)(pb + 4) = make_float4(bA[4], bA[5], bA[6], bA[7]);
}

__global__ __launch_bounds__(256)
void scan_pass2(const float* __restrict__ dtb, const float* __restrict__ xc,
                const float* __restrict__ dbl, const float* __restrict__ xz,
                const float* __restrict__ Alog, const float* __restrict__ Dp,
                const float* __restrict__ aPbuf, const float* __restrict__ bAbuf,
                unsigned short* __restrict__ y)
{
    int tid  = threadIdx.x;
    int half = tid & 1;
    int blk  = blockIdx.x;
    int dg   = blk & 15;
    int c    = (blk >> 4) & (NCHUNK - 1);
    int bb   = blk >> 9;
    int d    = dg * 128 + (tid >> 1);

    float A[8];
    {
        const float* pA = Alog + (size_t)d * D_STATE + half * 8;
        float4 v0 = *(const float4*)pA;
        float4 v1 = *(const float4*)(pA + 4);
        A[0] = -__expf(v0.x); A[1] = -__expf(v0.y);
        A[2] = -__expf(v0.z); A[3] = -__expf(v0.w);
        A[4] = -__expf(v1.x); A[5] = -__expf(v1.y);
        A[6] = -__expf(v1.z); A[7] = -__expf(v1.w);
    }
    float Dd = Dp[d];

    float h[8] = {0.f,0.f,0.f,0.f,0.f,0.f,0.f,0.f};

    // prefix compose over chunks [0, c)
    for (int cc = 0; cc < c; ++cc) {
        const float* pa = aPbuf + ((size_t)(bb * NCHUNK + cc) * D_INNER + d) * D_STATE + half * 8;
        const float* pb = bAbuf + ((size_t)(bb * NCHUNK + cc) * D_INNER + d) * D_STATE + half * 8;
        float4 a0 = *(const float4*)(pa + 0), a1 = *(const float4*)(pa + 4);
        float4 b0 = *(const float4*)(pb + 0), b1 = *(const float4*)(pb + 4);
        float av[8], bv[8];
        UNPK4(av, 0, a0) UNPK4(av, 4, a1)
        UNPK4(bv, 0, b0) UNPK4(bv, 4, b1)
        #pragma unroll
        for (int s = 0; s < 8; ++s) h[s] = h[s] * av[s] + bv[s];
    }

    size_t rowbase = (size_t)bb * LSEQ + (size_t)c * TCH;
    const float* pdt = dtb + rowbase * D_INNER + d;
    const float* pxc = xc  + rowbase * D_INNER + d;
    const float* pz  = xz  + rowbase * 2 * D_INNER + D_INNER + d;
    const float* pbc = dbl + rowbase * 96 + DT_RANK + half * 8;
    unsigned short* py = y + rowbase * D_INNER + d;

    // prefetch steps 0 (E) and 1 (O)
    float  dtE = pdt[0], xvE = pxc[0], zvE = pz[0];
    float4 BE0 = *(const float4*)pbc;
    float4 BE1 = *(const float4*)(pbc + 4);
    float4 CE0 = *(const float4*)(pbc + 16);
    float4 CE1 = *(const float4*)(pbc + 20);
    float  dtO = pdt[D_INNER], xvO = pxc[D_INNER], zvO = pz[2 * D_INNER];
    float4 BO0 = *(const float4*)(pbc + 96);
    float4 BO1 = *(const float4*)(pbc + 96 + 4);
    float4 CO0 = *(const float4*)(pbc + 96 + 16);
    float4 CO1 = *(const float4*)(pbc + 96 + 20);

    for (int t = 0; t < TCH; t += 2) {
        int t2 = (t + 2 < TCH) ? t + 2 : TCH - 1;
        int t3 = (t + 3 < TCH) ? t + 3 : TCH - 1;
        float  dtEn = pdt[(size_t)t2 * D_INNER], xvEn = pxc[(size_t)t2 * D_INNER];
        float  zvEn = pz[(size_t)t2 * 2 * D_INNER];
        float4 BE0n = *(const float4*)(pbc + (size_t)t2 * 96);
        float4 BE1n = *(const float4*)(pbc + (size_t)t2 * 96 + 4);
        float4 CE0n = *(const float4*)(pbc + (size_t)t2 * 96 + 16);
        float4 CE1n = *(const float4*)(pbc + (size_t)t2 * 96 + 20);
        float  dtOn = pdt[(size_t)t3 * D_INNER], xvOn = pxc[(size_t)t3 * D_INNER];
        float  zvOn = pz[(size_t)t3 * 2 * D_INNER];
        float4 BO0n = *(const float4*)(pbc + (size_t)t3 * 96);
        float4 BO1n = *(const float4*)(pbc + (size_t)t3 * 96 + 4);
        float4 CO0n = *(const float4*)(pbc + (size_t)t3 * 96 + 16);
        float4 CO1n = *(const float4*)(pbc + (size_t)t3 * 96 + 20);

        {   // step t
            float B[8], C[8];
            UNPK4(B, 0, BE0) UNPK4(B, 4, BE1)
            UNPK4(C, 0, CE0) UNPK4(C, 4, CE1)
            float dtx = dtE * xvE;
            float p = 0.f;
            #pragma unroll
            for (int s = 0; s < 8; ++s) {
                float a = __expf(dtE * A[s]);
                h[s] = h[s] * a + dtx * B[s];
                p += h[s] * C[s];
            }
            p += __shfl_xor(p, 1, 2);
            if (half == 0) {
                float sz = zvE / (1.f + __expf(-zvE));
                py[(size_t)t * D_INNER] = (unsigned short)bfbits((p + xvE * Dd) * sz);
            }
        }
        {   // step t+1
            float B[8], C[8];
            UNPK4(B, 0, BO0) UNPK4(B, 4, BO1)
            UNPK4(C, 0, CO0) UNPK4(C, 4, CO1)
            float dtx = dtO * xvO;
            float p = 0.f;
            #pragma unroll
            for (int s = 0; s < 8; ++s) {
                float a = __expf(dtO * A[s]);
                h[s] = h[s] * a + dtx * B[s];
                p += h[s] * C[s];
            }
            p += __shfl_xor(p, 1, 2);
            if (half == 0) {
                float sz = zvO / (1.f + __expf(-zvO));
                py[(size_t)(t + 1) * D_INNER] = (unsigned short)bfbits((p + xvO * Dd) * sz);
            }
        }
        dtE = dtEn; xvE = xvEn; zvE = zvEn;
        BE0 = BE0n; BE1 = BE1n; CE0 = CE0n; CE1 = CE1n;
        dtO = dtOn; xvO = xvOn; zvO = zvOn;
        BO0 = BO0n; BO1 = BO1n; CO0 = CO0n; CO1 = CO1n;
    }
}

// ---------------------------------------------------------------------------
extern "C" void kernel_launch(void* const* d_in, const int* in_sizes, int n_in,
                              void* d_out, int out_size, void* d_ws, size_t ws_size,
                              hipStream_t stream)
{
    const float* h_in  = (const float*)d_in[0];
    const float* iw    = (const float*)d_in[1];   // (4, 4096, 1024)
    const float* cw    = (const float*)d_in[2];   // (4, 2048, 4)
    const float* cb    = (const float*)d_in[3];   // (4, 2048)
    const float* xw    = (const float*)d_in[4];   // (4, 96, 2048)
    const float* dw    = (const float*)d_in[5];   // (4, 2048, 64)
    const float* db    = (const float*)d_in[6];   // (4, 2048)
    const float* Alog  = (const float*)d_in[7];   // (4, 2048, 16)
    const float* Dp    = (const float*)d_in[8];   // (4, 2048)
    const float* ow    = (const float*)d_in[9];   // (4, 1024, 2048)
    const float* nw    = (const float*)d_in[10];  // (4, 1024)
    const float* nb    = (const float*)d_in[11];  // (4, 1024)
    const float* nfw   = (const float*)d_in[12];  // (1024,)
    const float* nfb   = (const float*)d_in[13];  // (1024,)

    // workspace layout — identical total (25,362,432 floats)
    float* ws = (float*)d_ws;
    float* residual = ws;                       // 2,097,152
    float* hs       = residual + 2097152;       // 2,097,152
    float* xz       = hs + 2097152;             // 8,388,608  [r][4096]
    float* xc       = xz + 8388608;             // 4,194,304  [r][2048]
    float* dtb      = xc + 4194304;             // 4,194,304  [r][2048]
    float* dbl      = dtb + 4194304;            // 196,608    [r][96]
    float* y        = dbl + 196608;             // 4,194,304

    // aPbuf aliases hs (dead add_ln-consume .. scan_pass1); bAbuf = y[2M..4M).
    float* aPbuf = hs;
    float* bAbuf = y + 2097152;

    // bf16 / hi-lo staging, all in dead regions (timeline-disjoint):
    //  - wbuf_in (in_proj w bf16, y[0..2M))        : live f32_to_bf16 -> in_proj
    //  - hs_bf16 (LN out bf16, y[2M..3M))          : live add_ln -> in_proj
    //  - xc_hi (y[0..2M)), xc_lo (y[2M..4M))       : live conv -> xproj
    //  - y_bf16 (y[0..2M))                          : live scan_pass2 -> out_proj
    //  - weight hi/lo in hs[0..458K)                : live prep -> dtproj (pre-scan)
    //  - wbuf_out (out_proj w bf16, dtb[0..1M))    : live after scan
    unsigned short* wbuf_in  = (unsigned short*)y;
    unsigned short* hs_bf16  = (unsigned short*)(y + 2097152);
    unsigned short* y_bf16   = (unsigned short*)y;
    unsigned short* xc_hi    = (unsigned short*)y;
    unsigned short* xc_lo    = (unsigned short*)(y + 2097152);
    unsigned short* xwp_hi   = (unsigned short*)hs;
    unsigned short* xwp_lo   = (unsigned short*)(hs + 98304);
    unsigned short* dwp_hi   = (unsigned short*)(hs + 196608);
    unsigned short* dwp_lo   = (unsigned short*)(hs + 262144);
    unsigned short* dtl_hi   = (unsigned short*)(hs + 327680);
    unsigned short* dtl_lo   = (unsigned short*)(hs + 393216);
    unsigned short* wbuf_out = (unsigned short*)dtb;

    const float* cur_add = h_in;
    for (int i = 0; i < N_LAYER; ++i) {
        // residual add + LN, emit bf16
        add_ln_kernel<<<NROWS, 256, 0, stream>>>(cur_add, residual,
                                                 nw + i * D_MODEL, nb + i * D_MODEL,
                                                 hs_bf16, i == 0, 1);
        // convert in_proj weights -> bf16 (dead y space)
        f32_to_bf16_kernel<<<(2 * D_INNER * D_MODEL) / 1024, 256, 0, stream>>>(
            iw + (size_t)i * 2 * D_INNER * D_MODEL, wbuf_in);
        // in_proj (bf16 MFMA): -> xz [r][4096] fp32
        gemm_bf16_nt<<<dim3(2 * D_INNER / BBN, NROWS / BBM), 256, 0, stream>>>(
            hs_bf16, wbuf_in, xz, NROWS, 2 * D_INNER, D_MODEL);
        // conv + silu -> xc fp32 + hi/lo bf16 split (for MFMA x_proj)
        conv_silu_kernel<<<NB * LSEQ * D_INNER / 256, 256, 0, stream>>>(
            xz, cw + (size_t)i * D_INNER * D_CONV, cb + i * D_INNER, xc, xc_hi, xc_lo);
        // weight hi/lo prep (per layer; tiny)
        f32_to_hl_kernel<<<(96 * D_INNER) / 1024, 256, 0, stream>>>(
            xw + (size_t)i * 96 * D_INNER, xwp_hi, xwp_lo);
        f32_to_hl_kernel<<<(D_INNER * DT_RANK) / 1024, 256, 0, stream>>>(
            dw + (size_t)i * D_INNER * DT_RANK, dwp_hi, dwp_lo);
        // x_proj (hi/lo split-bf16 MFMA, split-K z=8): -> dbl [r][96]
        hipMemsetAsync(dbl, 0, 196608 * sizeof(float), stream);
        xproj_hl<<<dim3(NROWS / 32, 8), 256, 0, stream>>>(
            xc_hi, xc_lo, xwp_hi, xwp_lo, dbl);
        // extract dt-low cols -> compact hi/lo
        dtlow_hl_kernel<<<(NROWS * 16) / 256, 256, 0, stream>>>(dbl, dtl_hi, dtl_lo);
        // dt_proj (hi/lo split-bf16 MFMA + bias + softplus): -> dtb [r][2048]
        dtproj_hl<<<dim3(D_INNER / 128, NROWS / 64), 256, 0, stream>>>(
            dtl_hi, dtl_lo, dwp_hi, dwp_lo, db + i * D_INNER, dtb);
        // chunked selective scan — 2 lanes/d, 4096 waves, depth-2 pipeline
        scan_pass1<<<NB * NCHUNK * (D_INNER / 128), 256, 0, stream>>>(
            dtb, xc, dbl, Alog + (size_t)i * D_INNER * D_STATE, aPbuf, bAbuf);
        scan_pass2<<<NB * NCHUNK * (D_INNER / 128), 256, 0, stream>>>(
            dtb, xc, dbl, xz, Alog + (size_t)i * D_INNER * D_STATE, Dp + i * D_INNER,
            aPbuf, bAbuf, y_bf16);
        // convert out_proj weights -> bf16 (dead dtb space)
        f32_to_bf16_kernel<<<(D_MODEL * D_INNER) / 1024, 256, 0, stream>>>(
            ow + (size_t)i * D_MODEL * D_INNER, wbuf_out);
        // out_proj (bf16 MFMA): -> hs [r][1024] fp32
        gemm_bf16_nt<<<dim3(D_MODEL / BBN, NROWS / BBM), 256, 0, stream>>>(
            y_bf16, wbuf_out, hs, NROWS, D_MODEL, D_INNER);
        cur_add = hs;
    }
    add_ln_kernel<<<NROWS, 256, 0, stream>>>(hs, residual, nfw, nfb, d_out, 0, 0);
}